// Round 8
// baseline (380.922 us; speedup 1.0000x reference)
//
#include <hip/hip_runtime.h>
#include <hip/hip_cooperative_groups.h>
#include <cstddef>

namespace cg = cooperative_groups;

#define S_LEN 4096
#define C_DIM 256
#define NHEADS 8
#define HDIM 32

typedef __attribute__((ext_vector_type(8))) _Float16 half8;
typedef __attribute__((ext_vector_type(4))) _Float16 half4;
typedef __attribute__((ext_vector_type(2))) _Float16 h2t;
typedef __attribute__((ext_vector_type(2))) __fp16 fp16x2;
typedef __attribute__((ext_vector_type(4))) float floatx4;

// scale * log2(e) folded into W_q and bias_q at phase 0
#define SC2F ((float)(0.17677669529663687 * 1.4426950408889634))

// R8: single cooperative kernel, 256 blocks x 512 threads (1 block/CU, all
// co-resident). Phases: 0) GN stats + weight fp16 convert, 1) QKV GEMM with
// inline GN, 2) attention (R7 inner loop, unchanged), 3) proj GEMM+residual.
// grid.sync() between phases replaces 3 kernel launches + full drains.
__global__ __launch_bounds__(512) void fused_all(
    const float* __restrict__ x, const float* __restrict__ gamma,
    const float* __restrict__ beta, const float* __restrict__ qkv_w,
    const float* __restrict__ qkv_b, const float* __restrict__ proj_w,
    const float* __restrict__ proj_b, float* __restrict__ out,
    _Float16* __restrict__ wq, _Float16* __restrict__ wp,
    float* __restrict__ qbias, float* __restrict__ pstat,
    _Float16* __restrict__ qx, _Float16* __restrict__ kx,
    _Float16* __restrict__ vx, _Float16* __restrict__ ox)
{
  cg::grid_group grid = cg::this_grid();
  __shared__ __align__(16) char smem[37888];     // union of all phases
  const int tid = threadIdx.x;
  const int bid = blockIdx.x;
  const int lane = tid & 63, wv = tid >> 6;
  const int m = lane & 15, quad = lane >> 4;

  // ================== phase 0: GN stats + weight convert =================
  {
    // weight convert: 2 f32 per thread covers wq(196608) + wp(65536)
    const int gi = bid * 512 + tid;              // 0..131071
    const int i = gi * 2;
    if (i < 196608) {
      float2 v = *(const float2*)(qkv_w + i);
      const float sc = (i < 65536) ? SC2F : 1.f; // q rows
      *(h2t*)(wq + i) = (h2t){ (_Float16)(v.x * sc), (_Float16)(v.y * sc) };
    } else {
      const int j = i - 196608;
      float2 v = *(const float2*)(proj_w + j);
      *(h2t*)(wp + j) = (h2t){ (_Float16)v.x, (_Float16)v.y };
    }
    if (bid == 0 && tid < 256) {
      #pragma unroll
      for (int j = 0; j < 3; ++j) {
        const int i2 = tid + j * 256;
        float bv = qkv_b[i2];
        if (i2 < 256) bv *= SC2F;
        qbias[i2] = bv;
      }
    }
    // GN partial stats: job = bid*2 + (tid>=256); 16K floats per job
    float* red = (float*)smem;                   // [2][2][4]
    const int h = tid >> 8, t = tid & 255;
    const int job = bid * 2 + h;
    const int gb = job >> 3, e = job & 7;
    const int g = gb & 31, b = gb >> 5;
    const float4* x4 = (const float4*)(x + ((size_t)b * C_DIM + g * 8) * S_LEN + e * 4096);
    float sum = 0.f, sumsq = 0.f;
    #pragma unroll
    for (int i2 = 0; i2 < 4; ++i2) {
      float4 v = x4[t + i2 * 256];
      sum += v.x + v.y + v.z + v.w;
      sumsq += v.x * v.x + v.y * v.y + v.z * v.z + v.w * v.w;
    }
    for (int off = 1; off < 64; off <<= 1) {
      sum += __shfl_xor(sum, off, 64);
      sumsq += __shfl_xor(sumsq, off, 64);
    }
    const int w4 = (tid >> 6) & 3;
    if (lane == 0) { red[(h * 2 + 0) * 4 + w4] = sum; red[(h * 2 + 1) * 4 + w4] = sumsq; }
    __syncthreads();
    if (t == 0) {
      pstat[job * 2 + 0] = red[(h*2+0)*4+0] + red[(h*2+0)*4+1] + red[(h*2+0)*4+2] + red[(h*2+0)*4+3];
      pstat[job * 2 + 1] = red[(h*2+1)*4+0] + red[(h*2+1)*4+1] + red[(h*2+1)*4+2] + red[(h*2+1)*4+3];
    }
  }
  __threadfence();
  grid.sync();

  // ================== phase 1: QKV GEMM + inline GN ======================
  {
    _Float16* Ld = (_Float16*)smem;              // stage [32][264]; v-stage [256][40]
    const int b = bid >> 7;
    const int s0 = (bid & 127) * 32;
    {  // inline GN: x (c,s) f32 -> Ld[s][c] f16
      const int c0 = (tid & 127) * 2, c1 = c0 + 1;
      const int sh = tid >> 7;                   // 0..3, 8 s each
      const int gb = b * 32 + (c0 >> 3);
      float s = 0.f, sq = 0.f;
      #pragma unroll
      for (int e = 0; e < 8; ++e) {
        s  += pstat[(gb * 8 + e) * 2 + 0];
        sq += pstat[(gb * 8 + e) * 2 + 1];
      }
      const float mean = s * (1.f / 32768.f);
      const float rstd = rsqrtf(sq * (1.f / 32768.f) - mean * mean + 1e-6f);
      const float ga0 = gamma[c0] * rstd, be0 = beta[c0] - mean * ga0;
      const float ga1 = gamma[c1] * rstd, be1 = beta[c1] - mean * ga1;
      const float4* xa = (const float4*)(x + ((size_t)b * C_DIM + c0) * S_LEN + s0 + sh * 8);
      const float4* xc = (const float4*)(x + ((size_t)b * C_DIM + c1) * S_LEN + s0 + sh * 8);
      #pragma unroll
      for (int j = 0; j < 2; ++j) {
        float4 a = xa[j], c = xc[j];
        int sl = sh * 8 + j * 4;
        *(h2t*)&Ld[(sl + 0) * 264 + c0] = (h2t){ (_Float16)(a.x * ga0 + be0), (_Float16)(c.x * ga1 + be1) };
        *(h2t*)&Ld[(sl + 1) * 264 + c0] = (h2t){ (_Float16)(a.y * ga0 + be0), (_Float16)(c.y * ga1 + be1) };
        *(h2t*)&Ld[(sl + 2) * 264 + c0] = (h2t){ (_Float16)(a.z * ga0 + be0), (_Float16)(c.z * ga1 + be1) };
        *(h2t*)&Ld[(sl + 3) * 264 + c0] = (h2t){ (_Float16)(a.w * ga0 + be0), (_Float16)(c.w * ga1 + be1) };
      }
    }
    __syncthreads();

    // wave wv owns mt tiles {wv + 8j}: j=0,1 -> q; 2,3 -> k; 4,5 -> v
    const _Float16* wrow[6];
    #pragma unroll
    for (int j = 0; j < 6; ++j)
      wrow[j] = wq + (size_t)((wv + 8 * j) * 16 + m) * C_DIM + quad * 8;
    const _Float16* lp = &Ld[m * 264 + quad * 8];

    floatx4 acc[6][2];
    #pragma unroll
    for (int j = 0; j < 6; ++j) {
      acc[j][0] = (floatx4){0.f,0.f,0.f,0.f};
      acc[j][1] = (floatx4){0.f,0.f,0.f,0.f};
    }
    #pragma unroll 2
    for (int k0 = 0; k0 < C_DIM; k0 += 32) {
      half8 b0 = *(const half8*)(lp + k0);
      half8 b1 = *(const half8*)(lp + 16 * 264 + k0);
      #pragma unroll
      for (int j = 0; j < 6; ++j) {
        half8 a = *(const half8*)(wrow[j] + k0);
        acc[j][0] = __builtin_amdgcn_mfma_f32_16x16x32_f16(a, b0, acc[j][0], 0, 0, 0);
        acc[j][1] = __builtin_amdgcn_mfma_f32_16x16x32_f16(a, b1, acc[j][1], 0, 0, 0);
      }
    }
    __syncthreads();                             // Ld b-frag reads complete
    // q/k epilogue (j=0..3)
    #pragma unroll
    for (int j = 0; j < 4; ++j) {
      const int ob = (wv + 8 * j) * 16 + quad * 4;
      const float bv0 = qbias[ob], bv1 = qbias[ob + 1],
                  bv2 = qbias[ob + 2], bv3 = qbias[ob + 3];
      _Float16* dst = (ob < 256) ? qx : kx;
      const int oo = ob & 255, n = oo >> 5, d0 = oo & 31;
      #pragma unroll
      for (int sub = 0; sub < 2; ++sub) {
        int s = s0 + sub * 16 + m;
        half4 h = { (_Float16)(acc[j][sub][0] + bv0), (_Float16)(acc[j][sub][1] + bv1),
                    (_Float16)(acc[j][sub][2] + bv2), (_Float16)(acc[j][sub][3] + bv3) };
        *(half4*)(dst + (((size_t)b * NHEADS + n) * S_LEN + s) * HDIM + d0) = h;
      }
    }
    // v epilogue via LDS transpose [256 ch][32 s] stride 40
    _Float16* VLd = Ld;
    #pragma unroll
    for (int j = 4; j < 6; ++j) {
      const int ob = (wv + 8 * j) * 16 + quad * 4;
      const int lch = ob - 512;
      const float bv0 = qbias[ob], bv1 = qbias[ob + 1],
                  bv2 = qbias[ob + 2], bv3 = qbias[ob + 3];
      #pragma unroll
      for (int sub = 0; sub < 2; ++sub) {
        int s = sub * 16 + m;
        VLd[(lch + 0) * 40 + s] = (_Float16)(acc[j][sub][0] + bv0);
        VLd[(lch + 1) * 40 + s] = (_Float16)(acc[j][sub][1] + bv1);
        VLd[(lch + 2) * 40 + s] = (_Float16)(acc[j][sub][2] + bv2);
        VLd[(lch + 3) * 40 + s] = (_Float16)(acc[j][sub][3] + bv3);
      }
    }
    __syncthreads();
    {
      const int ch = tid >> 1, sh = tid & 1;
      const int n = ch >> 5, d = ch & 31;
      _Float16* dst = vx + ((size_t)(b * NHEADS + n) * HDIM + d) * S_LEN + s0 + sh * 16;
      const _Float16* src = VLd + ch * 40 + sh * 16;
      *(half8*)(dst + 0) = *(const half8*)(src + 0);
      *(half8*)(dst + 8) = *(const half8*)(src + 8);
    }
  }
  __threadfence();
  grid.sync();

  // ================== phase 2: attention (R7 inner loop) =================
  {
    _Float16* KlB = (_Float16*)smem;             // 2 bufs x 5120 halfs
    _Float16* VlB = (_Float16*)(smem + 20480);   // 2 bufs x 4352 halfs
    const int qc = bid & 15, n = (bid >> 4) & 7, b = bid >> 7;
    const int q0 = qc * 256 + wv * 32;
    const int bh = b * NHEADS + n;

    const _Float16* qb = qx + (size_t)bh * S_LEN * HDIM;
    const _Float16* kb = kx + (size_t)bh * S_LEN * HDIM;
    const _Float16* vb = vx + (size_t)bh * HDIM * S_LEN;

    half8 qfA = *(const half8*)(qb + (size_t)(q0 + m) * HDIM + quad * 8);
    half8 qfB = *(const half8*)(qb + (size_t)(q0 + 16 + m) * HDIM + quad * 8);

    const int krow = wv * 16 + (lane >> 2), kc = (lane & 3) * 8;
    const int vrow = wv * 4 + (lane >> 4), vc = (lane & 15) * 8;
    const _Float16* kg = kb + (size_t)krow * HDIM + kc;
    const _Float16* vg = vb + (size_t)vrow * S_LEN + vc;
    const int klds = krow * 40 + kc;
    const int vlds = vrow * 136 + vc;

    int4 kreg = *(const int4*)kg;
    int4 vreg = *(const int4*)vg;
    const _Float16* kgp = kg + 128 * HDIM;
    const _Float16* vgp = vg + 128;

    floatx4 oA0 = {0.f,0.f,0.f,0.f}, oA1 = oA0, oB0 = oA0, oB1 = oA0;
    float lA0 = 0.f, lA1 = 0.f, lB0 = 0.f, lB1 = 0.f;
    const fp16x2 one2 = { (__fp16)1.0f, (__fp16)1.0f };
    const floatx4 zz = {0.f,0.f,0.f,0.f};

    #pragma unroll 2
    for (int it = 0; it < 32; ++it) {            // 32 x 128 keys = 4096
      const int bufi = it & 1;
      *(int4*)(KlB + bufi * 5120 + klds) = kreg;
      *(int4*)(VlB + bufi * 4352 + vlds) = vreg;
      kreg = *(const int4*)kgp; kgp += 128 * HDIM;
      vreg = *(const int4*)vgp; vgp += 128;
      __syncthreads();
      const _Float16* Kb = KlB + bufi * 5120;
      const _Float16* Vb = VlB + bufi * 4352;

      #pragma unroll
      for (int t = 0; t < 8; ++t) {
        const int tt = (t + wv) & 7;             // per-wave phase rotation
        half8 kf  = *(const half8*)(Kb + (tt * 16 + m) * 40 + quad * 8);
        half4 vf0 = *(const half4*)(Vb + m * 136 + tt * 16 + quad * 4);
        half4 vf1 = *(const half4*)(Vb + (16 + m) * 136 + tt * 16 + quad * 4);
        __builtin_amdgcn_s_setprio(1);
        floatx4 sA = __builtin_amdgcn_mfma_f32_16x16x32_f16(kf, qfA, zz, 0, 0, 0);
        floatx4 sB = __builtin_amdgcn_mfma_f32_16x16x32_f16(kf, qfB, zz, 0, 0, 0);
        __builtin_amdgcn_s_setprio(0);
        float eA0 = __builtin_amdgcn_exp2f(sA[0]);
        float eA1 = __builtin_amdgcn_exp2f(sA[1]);
        float eA2 = __builtin_amdgcn_exp2f(sA[2]);
        float eA3 = __builtin_amdgcn_exp2f(sA[3]);
        float eB0 = __builtin_amdgcn_exp2f(sB[0]);
        float eB1 = __builtin_amdgcn_exp2f(sB[1]);
        float eB2 = __builtin_amdgcn_exp2f(sB[2]);
        float eB3 = __builtin_amdgcn_exp2f(sB[3]);
        half4 pA, pB;
        fp16x2 pAlo = __builtin_amdgcn_cvt_pkrtz(eA0, eA1);
        fp16x2 pAhi = __builtin_amdgcn_cvt_pkrtz(eA2, eA3);
        fp16x2 pBlo = __builtin_amdgcn_cvt_pkrtz(eB0, eB1);
        fp16x2 pBhi = __builtin_amdgcn_cvt_pkrtz(eB2, eB3);
        *(fp16x2*)&pA = pAlo; *((fp16x2*)&pA + 1) = pAhi;
        *(fp16x2*)&pB = pBlo; *((fp16x2*)&pB + 1) = pBhi;
        lA0 = __builtin_amdgcn_fdot2(pAlo, one2, lA0, false);
        lA1 = __builtin_amdgcn_fdot2(pAhi, one2, lA1, false);
        lB0 = __builtin_amdgcn_fdot2(pBlo, one2, lB0, false);
        lB1 = __builtin_amdgcn_fdot2(pBhi, one2, lB1, false);
        __builtin_amdgcn_s_setprio(1);
        oA0 = __builtin_amdgcn_mfma_f32_16x16x16f16(vf0, pA, oA0, 0, 0, 0);
        oA1 = __builtin_amdgcn_mfma_f32_16x16x16f16(vf1, pA, oA1, 0, 0, 0);
        oB0 = __builtin_amdgcn_mfma_f32_16x16x16f16(vf0, pB, oB0, 0, 0, 0);
        oB1 = __builtin_amdgcn_mfma_f32_16x16x16f16(vf1, pB, oB1, 0, 0, 0);
        __builtin_amdgcn_s_setprio(0);
      }
    }
    float lA = lA0 + lA1, lB = lB0 + lB1;
    lA += __shfl_xor(lA, 16, 64); lA += __shfl_xor(lA, 32, 64);
    lB += __shfl_xor(lB, 16, 64); lB += __shfl_xor(lB, 32, 64);
    const float rA = 1.f / lA, rB = 1.f / lB;
    _Float16* obase = ox + ((size_t)bh * S_LEN) * HDIM;
    {
      _Float16* oh = obase + (size_t)(q0 + m) * HDIM;
      half4 h0 = { (_Float16)(oA0[0] * rA), (_Float16)(oA0[1] * rA),
                   (_Float16)(oA0[2] * rA), (_Float16)(oA0[3] * rA) };
      half4 h1 = { (_Float16)(oA1[0] * rA), (_Float16)(oA1[1] * rA),
                   (_Float16)(oA1[2] * rA), (_Float16)(oA1[3] * rA) };
      *(half4*)(oh + quad * 4) = h0;
      *(half4*)(oh + 16 + quad * 4) = h1;
    }
    {
      _Float16* oh = obase + (size_t)(q0 + 16 + m) * HDIM;
      half4 h0 = { (_Float16)(oB0[0] * rB), (_Float16)(oB0[1] * rB),
                   (_Float16)(oB0[2] * rB), (_Float16)(oB0[3] * rB) };
      half4 h1 = { (_Float16)(oB1[0] * rB), (_Float16)(oB1[1] * rB),
                   (_Float16)(oB1[2] * rB), (_Float16)(oB1[3] * rB) };
      *(half4*)(oh + quad * 4) = h0;
      *(half4*)(oh + 16 + quad * 4) = h1;
    }
  }
  __threadfence();
  grid.sync();

  // ================== phase 3: proj GEMM + residual ======================
  {
    const int b = bid >> 7;
    const int s0 = (bid & 127) * 32;
    const int mtb = wv * 2;                      // 16 mt tiles across 8 waves
    const _Float16* wrow0 = wp + (size_t)((mtb + 0) * 16 + m) * C_DIM + quad * 8;
    const _Float16* wrow1 = wp + (size_t)((mtb + 1) * 16 + m) * C_DIM + quad * 8;
    floatx4 acc[2][2];
    acc[0][0] = (floatx4){0.f,0.f,0.f,0.f}; acc[0][1] = acc[0][0];
    acc[1][0] = acc[0][0]; acc[1][1] = acc[0][0];

    #pragma unroll
    for (int k0 = 0; k0 < C_DIM; k0 += 32) {
      const int n = k0 >> 5;
      const int d0 = quad * 8;
      half8 bf[2];
      #pragma unroll
      for (int sub = 0; sub < 2; ++sub) {
        size_t idx = (((size_t)(b * NHEADS + n)) * S_LEN + s0 + sub * 16 + m) * HDIM + d0;
        bf[sub] = *(const half8*)(ox + idx);
      }
      half8 af0 = *(const half8*)(wrow0 + k0);
      half8 af1 = *(const half8*)(wrow1 + k0);
      #pragma unroll
      for (int sub = 0; sub < 2; ++sub) {
        acc[0][sub] = __builtin_amdgcn_mfma_f32_16x16x32_f16(af0, bf[sub], acc[0][sub], 0, 0, 0);
        acc[1][sub] = __builtin_amdgcn_mfma_f32_16x16x32_f16(af1, bf[sub], acc[1][sub], 0, 0, 0);
      }
    }
    #pragma unroll
    for (int j = 0; j < 2; ++j)
      #pragma unroll
      for (int sub = 0; sub < 2; ++sub) {
        int s = s0 + sub * 16 + m;
        #pragma unroll
        for (int r = 0; r < 4; ++r) {
          int c = (mtb + j) * 16 + quad * 4 + r;
          size_t idx = ((size_t)b * C_DIM + c) * S_LEN + s;
          out[idx] = x[idx] + acc[j][sub][r] + proj_b[c];
        }
      }
  }
}

// ---------------------------------------------------------------- launch
extern "C" void kernel_launch(void* const* d_in, const int* in_sizes, int n_in,
                              void* d_out, int out_size, void* d_ws, size_t ws_size,
                              hipStream_t stream) {
  const float* x        = (const float*)d_in[0];
  const float* gn_gamma = (const float*)d_in[1];
  const float* gn_beta  = (const float*)d_in[2];
  const float* qkv_w    = (const float*)d_in[3];
  const float* qkv_b    = (const float*)d_in[4];
  const float* proj_w   = (const float*)d_in[5];
  const float* proj_b   = (const float*)d_in[6];
  float* out = (float*)d_out;

  const size_t n1 = (size_t)2 * S_LEN * C_DIM;   // 2M elems = 4 MB f16
  char* ws = (char*)d_ws;
  _Float16* qx  = (_Float16*)ws;                 // (B,NH,S,hd)
  _Float16* kx  = qx + n1;                       // (B,NH,S,hd)
  _Float16* vx  = kx + n1;                       // (B,NH,hd,S)
  _Float16* wq  = vx + n1;                       // 768x256 f16
  _Float16* wp  = wq + 768 * 256;                // 256x256 f16
  float*    qbias = (float*)(wp + 256 * 256);    // 768 f32
  float*    pstat = qbias + 768;                 // 512*2 f32
  _Float16* ox  = (_Float16*)(pstat + 1024);     // (B,NH,S,hd) f16 = 4 MB

  void* args[] = {
    (void*)&x, (void*)&gn_gamma, (void*)&gn_beta, (void*)&qkv_w,
    (void*)&qkv_b, (void*)&proj_w, (void*)&proj_b, (void*)&out,
    (void*)&wq, (void*)&wp, (void*)&qbias, (void*)&pstat,
    (void*)&qx, (void*)&kx, (void*)&vx, (void*)&ox
  };
  hipLaunchCooperativeKernel((const void*)fused_all, dim3(256), dim3(512),
                             args, 0, stream);
}

// Round 9
// 236.484 us; speedup vs baseline: 1.6108x; 1.6108x over previous
//
#include <hip/hip_runtime.h>
#include <cstddef>

#define S_LEN 4096
#define C_DIM 256
#define NHEADS 8
#define HDIM 32

typedef __attribute__((ext_vector_type(8))) _Float16 half8;
typedef __attribute__((ext_vector_type(4))) _Float16 half4;
typedef __attribute__((ext_vector_type(2))) _Float16 h2t;
typedef __attribute__((ext_vector_type(2))) __fp16 fp16x2;
typedef __attribute__((ext_vector_type(4))) float floatx4;

// scale * log2(e) folded into W_q and bias_q at prep time
#define SC2F ((float)(0.17677669529663687 * 1.4426950408889634))

// ---------------------------------------------------------------- prep + GN partial stats
__global__ __launch_bounds__(256) void prep_stats(
    const float* __restrict__ qkv_w, const float* __restrict__ proj_w,
    const float* __restrict__ qkv_b, const float* __restrict__ x,
    _Float16* __restrict__ wq, _Float16* __restrict__ wp,
    float* __restrict__ qbias, float* __restrict__ pstat)
{
  const int blk = blockIdx.x;
  const int tid = threadIdx.x;
  if (blk < 512) {
    __shared__ float red[2][4];
    const int gb = blk >> 3, e = blk & 7;       // gb = b*32+g
    const int g = gb & 31, b = gb >> 5;
    const float* xb = x + ((size_t)b * C_DIM + g * 8) * S_LEN + e * 4096;
    const float4* x4 = (const float4*)xb;       // 1024 float4
    float sum = 0.f, sumsq = 0.f;
    #pragma unroll
    for (int i = 0; i < 4; ++i) {
      float4 v = x4[tid + i * 256];
      sum += v.x + v.y + v.z + v.w;
      sumsq += v.x * v.x + v.y * v.y + v.z * v.z + v.w * v.w;
    }
    for (int off = 1; off < 64; off <<= 1) {
      sum += __shfl_xor(sum, off, 64);
      sumsq += __shfl_xor(sumsq, off, 64);
    }
    const int wv = tid >> 6, lane = tid & 63;
    if (lane == 0) { red[0][wv] = sum; red[1][wv] = sumsq; }
    __syncthreads();
    if (tid == 0) {
      pstat[(gb * 8 + e) * 2 + 0] = red[0][0] + red[0][1] + red[0][2] + red[0][3];
      pstat[(gb * 8 + e) * 2 + 1] = red[1][0] + red[1][1] + red[1][2] + red[1][3];
    }
  } else if (blk < 704) {
    // Wq: 192 blocks x 1024 elems (float4 per thread)
    const int i = (blk - 512) * 1024 + tid * 4;
    float4 v = *(const float4*)(qkv_w + i);
    const float sc = (i < 65536) ? SC2F : 1.f;   // q rows (first 256x256)
    half4 h = { (_Float16)(v.x * sc), (_Float16)(v.y * sc),
                (_Float16)(v.z * sc), (_Float16)(v.w * sc) };
    *(half4*)(wq + i) = h;
  } else if (blk < 768) {
    // Wp: 64 blocks x 1024 elems
    const int i = (blk - 704) * 1024 + tid * 4;
    float4 v = *(const float4*)(proj_w + i);
    half4 h = { (_Float16)v.x, (_Float16)v.y, (_Float16)v.z, (_Float16)v.w };
    *(half4*)(wp + i) = h;
  } else {
    // bias: 768 values
    #pragma unroll
    for (int j = 0; j < 3; ++j) {
      const int i = tid + j * 256;
      float bv = qkv_b[i];
      if (i < 256) bv *= SC2F;
      qbias[i] = bv;
    }
  }
}

// ---------------------------------------------------------------- QKV GEMM + inline GN
// R7 state (unchanged): one block = all 768 out rows for a 32-s slice;
// x read exactly once with GN applied during LDS stage.
__global__ __launch_bounds__(512) void qkv_gn_gemm(
    const _Float16* __restrict__ W, const float* __restrict__ bias,
    const float* __restrict__ x, const float* __restrict__ gamma,
    const float* __restrict__ beta, const float* __restrict__ pstat,
    _Float16* __restrict__ qo, _Float16* __restrict__ ko_,
    _Float16* __restrict__ vo)
{
  __shared__ __align__(16) _Float16 Ld[256 * 40];
  const int tid = threadIdx.x;
  const int b = blockIdx.y;
  const int s0 = blockIdx.x * 32;

  {  // ---- inline GN apply: x (c,s) f32 -> Ld[s][c] f16 (stride 264)
    const int c0 = (tid & 127) * 2, c1 = c0 + 1;
    const int sh = tid >> 7;                       // 0..3, 8 s each
    const int gb = b * 32 + (c0 >> 3);
    float s = 0.f, sq = 0.f;
    #pragma unroll
    for (int e = 0; e < 8; ++e) {
      s  += pstat[(gb * 8 + e) * 2 + 0];
      sq += pstat[(gb * 8 + e) * 2 + 1];
    }
    const float mean = s * (1.f / 32768.f);
    const float rstd = rsqrtf(sq * (1.f / 32768.f) - mean * mean + 1e-6f);
    const float ga0 = gamma[c0] * rstd, be0 = beta[c0] - mean * ga0;
    const float ga1 = gamma[c1] * rstd, be1 = beta[c1] - mean * ga1;
    const float4* xa = (const float4*)(x + ((size_t)b * C_DIM + c0) * S_LEN + s0 + sh * 8);
    const float4* xc = (const float4*)(x + ((size_t)b * C_DIM + c1) * S_LEN + s0 + sh * 8);
    #pragma unroll
    for (int j = 0; j < 2; ++j) {
      float4 a = xa[j], c = xc[j];
      int sl = sh * 8 + j * 4;
      *(h2t*)&Ld[(sl + 0) * 264 + c0] = (h2t){ (_Float16)(a.x * ga0 + be0), (_Float16)(c.x * ga1 + be1) };
      *(h2t*)&Ld[(sl + 1) * 264 + c0] = (h2t){ (_Float16)(a.y * ga0 + be0), (_Float16)(c.y * ga1 + be1) };
      *(h2t*)&Ld[(sl + 2) * 264 + c0] = (h2t){ (_Float16)(a.z * ga0 + be0), (_Float16)(c.z * ga1 + be1) };
      *(h2t*)&Ld[(sl + 3) * 264 + c0] = (h2t){ (_Float16)(a.w * ga0 + be0), (_Float16)(c.w * ga1 + be1) };
    }
  }
  __syncthreads();

  const int lane = tid & 63, wv = tid >> 6;       // 8 waves
  const int m = lane & 15, quad = lane >> 4;
  const _Float16* wrow[6];
  #pragma unroll
  for (int j = 0; j < 6; ++j)
    wrow[j] = W + (size_t)((wv + 8 * j) * 16 + m) * C_DIM + quad * 8;
  const _Float16* lp = &Ld[m * 264 + quad * 8];

  floatx4 acc[6][2];
  #pragma unroll
  for (int j = 0; j < 6; ++j) {
    acc[j][0] = (floatx4){0.f,0.f,0.f,0.f};
    acc[j][1] = (floatx4){0.f,0.f,0.f,0.f};
  }

  #pragma unroll 2
  for (int k0 = 0; k0 < C_DIM; k0 += 32) {
    half8 b0 = *(const half8*)(lp + k0);
    half8 b1 = *(const half8*)(lp + 16 * 264 + k0);
    #pragma unroll
    for (int j = 0; j < 6; ++j) {
      half8 a = *(const half8*)(wrow[j] + k0);
      acc[j][0] = __builtin_amdgcn_mfma_f32_16x16x32_f16(a, b0, acc[j][0], 0, 0, 0);
      acc[j][1] = __builtin_amdgcn_mfma_f32_16x16x32_f16(a, b1, acc[j][1], 0, 0, 0);
    }
  }

  __syncthreads();
  #pragma unroll
  for (int j = 0; j < 4; ++j) {
    const int ob = (wv + 8 * j) * 16 + quad * 4;  // 0..511
    const float bv0 = bias[ob], bv1 = bias[ob + 1],
                bv2 = bias[ob + 2], bv3 = bias[ob + 3];
    _Float16* dst = (ob < 256) ? qo : ko_;
    const int oo = ob & 255, n = oo >> 5, d0 = oo & 31;
    #pragma unroll
    for (int sub = 0; sub < 2; ++sub) {
      int s = s0 + sub * 16 + m;
      half4 h = { (_Float16)(acc[j][sub][0] + bv0), (_Float16)(acc[j][sub][1] + bv1),
                  (_Float16)(acc[j][sub][2] + bv2), (_Float16)(acc[j][sub][3] + bv3) };
      *(half4*)(dst + (((size_t)b * NHEADS + n) * S_LEN + s) * HDIM + d0) = h;
    }
  }
  _Float16* VLd = Ld;
  #pragma unroll
  for (int j = 4; j < 6; ++j) {
    const int ob = (wv + 8 * j) * 16 + quad * 4;  // 512..767
    const int lch = ob - 512;
    const float bv0 = bias[ob], bv1 = bias[ob + 1],
                bv2 = bias[ob + 2], bv3 = bias[ob + 3];
    #pragma unroll
    for (int sub = 0; sub < 2; ++sub) {
      int s = sub * 16 + m;
      VLd[(lch + 0) * 40 + s] = (_Float16)(acc[j][sub][0] + bv0);
      VLd[(lch + 1) * 40 + s] = (_Float16)(acc[j][sub][1] + bv1);
      VLd[(lch + 2) * 40 + s] = (_Float16)(acc[j][sub][2] + bv2);
      VLd[(lch + 3) * 40 + s] = (_Float16)(acc[j][sub][3] + bv3);
    }
  }
  __syncthreads();
  {
    const int ch = tid >> 1, sh = tid & 1;
    const int n = ch >> 5, d = ch & 31;
    _Float16* dst = vo + ((size_t)(b * NHEADS + n) * HDIM + d) * S_LEN + s0 + sh * 16;
    const _Float16* src = VLd + ch * 40 + sh * 16;
    *(half8*)(dst + 0) = *(const half8*)(src + 0);
    *(half8*)(dst + 8) = *(const half8*)(src + 8);
  }
}

// ---------------------------------------------------------------- Fused attention + proj
// R9: block = (32-row s-slice, b); wave wv <-> head wv. Attention streams
// K/V fragments per-lane straight from global (L2-resident), register
// double-buffered 64 keys ahead. NO barriers in the hot loop (waves fully
// independent -> no convoy). Epilogue: normalize -> o to LDS [32][264] ->
// one __syncthreads -> proj GEMM + residual, out written directly.
#define LOADG(KF, V0, V1, G) do {                                         \
    const int _g4 = (G) * 4;                                              \
    _Pragma("unroll")                                                     \
    for (int _t = 0; _t < 4; ++_t) {                                      \
      KF[_t] = *(const half8*)(kaddr + (size_t)(_g4 + _t) * 512);         \
      V0[_t] = *(const half4*)(vaddr0 + (_g4 + _t) * 16);                 \
      V1[_t] = *(const half4*)(vaddr1 + (_g4 + _t) * 16);                 \
    }                                                                     \
  } while (0)

#define COMPG(KF, V0, V1) do {                                            \
    _Pragma("unroll")                                                     \
    for (int _t = 0; _t < 4; ++_t) {                                      \
      __builtin_amdgcn_s_setprio(1);                                      \
      floatx4 sA = __builtin_amdgcn_mfma_f32_16x16x32_f16(KF[_t], qfA, zz, 0, 0, 0); \
      floatx4 sB = __builtin_amdgcn_mfma_f32_16x16x32_f16(KF[_t], qfB, zz, 0, 0, 0); \
      __builtin_amdgcn_s_setprio(0);                                      \
      float eA0 = __builtin_amdgcn_exp2f(sA[0]);                          \
      float eA1 = __builtin_amdgcn_exp2f(sA[1]);                          \
      float eA2 = __builtin_amdgcn_exp2f(sA[2]);                          \
      float eA3 = __builtin_amdgcn_exp2f(sA[3]);                          \
      float eB0 = __builtin_amdgcn_exp2f(sB[0]);                          \
      float eB1 = __builtin_amdgcn_exp2f(sB[1]);                          \
      float eB2 = __builtin_amdgcn_exp2f(sB[2]);                          \
      float eB3 = __builtin_amdgcn_exp2f(sB[3]);                          \
      half4 pA, pB;                                                       \
      fp16x2 pAlo = __builtin_amdgcn_cvt_pkrtz(eA0, eA1);                 \
      fp16x2 pAhi = __builtin_amdgcn_cvt_pkrtz(eA2, eA3);                 \
      fp16x2 pBlo = __builtin_amdgcn_cvt_pkrtz(eB0, eB1);                 \
      fp16x2 pBhi = __builtin_amdgcn_cvt_pkrtz(eB2, eB3);                 \
      *(fp16x2*)&pA = pAlo; *((fp16x2*)&pA + 1) = pAhi;                   \
      *(fp16x2*)&pB = pBlo; *((fp16x2*)&pB + 1) = pBhi;                   \
      lA0 = __builtin_amdgcn_fdot2(pAlo, one2, lA0, false);               \
      lA1 = __builtin_amdgcn_fdot2(pAhi, one2, lA1, false);               \
      lB0 = __builtin_amdgcn_fdot2(pBlo, one2, lB0, false);               \
      lB1 = __builtin_amdgcn_fdot2(pBhi, one2, lB1, false);               \
      __builtin_amdgcn_s_setprio(1);                                      \
      oA0 = __builtin_amdgcn_mfma_f32_16x16x16f16(V0[_t], pA, oA0, 0, 0, 0); \
      oA1 = __builtin_amdgcn_mfma_f32_16x16x16f16(V1[_t], pA, oA1, 0, 0, 0); \
      oB0 = __builtin_amdgcn_mfma_f32_16x16x16f16(V0[_t], pB, oB0, 0, 0, 0); \
      oB1 = __builtin_amdgcn_mfma_f32_16x16x16f16(V1[_t], pB, oB1, 0, 0, 0); \
      __builtin_amdgcn_s_setprio(0);                                      \
    }                                                                     \
  } while (0)

__global__ __launch_bounds__(512, 2) void attn_proj(
    const _Float16* __restrict__ q, const _Float16* __restrict__ k,
    const _Float16* __restrict__ v, const _Float16* __restrict__ wp,
    const float* __restrict__ pbias, const float* __restrict__ x,
    float* __restrict__ out)
{
  __shared__ __align__(16) _Float16 Lo[32 * 264];   // o slice [32 s][264]
  const int tid = threadIdx.x;
  const int lane = tid & 63, wv = tid >> 6;         // wv = head
  const int m = lane & 15, quad = lane >> 4;
  const int b = blockIdx.y;
  const int sbase = blockIdx.x * 32;                // 32-row s-slice
  const int bh = b * NHEADS + wv;

  const _Float16* qb = q + (size_t)bh * S_LEN * HDIM;
  const _Float16* kaddr = k + (size_t)bh * S_LEN * HDIM + m * HDIM + quad * 8;
  const _Float16* vb = v + (size_t)bh * HDIM * S_LEN;
  const _Float16* vaddr0 = vb + (size_t)m * S_LEN + quad * 4;
  const _Float16* vaddr1 = vb + (size_t)(16 + m) * S_LEN + quad * 4;

  half8 qfA = *(const half8*)(qb + (size_t)(sbase + m) * HDIM + quad * 8);
  half8 qfB = *(const half8*)(qb + (size_t)(sbase + 16 + m) * HDIM + quad * 8);

  floatx4 oA0 = {0.f,0.f,0.f,0.f}, oA1 = oA0, oB0 = oA0, oB1 = oA0;
  float lA0 = 0.f, lA1 = 0.f, lB0 = 0.f, lB1 = 0.f;
  const fp16x2 one2 = { (__fp16)1.0f, (__fp16)1.0f };
  const floatx4 zz = {0.f,0.f,0.f,0.f};

  half8 kfA[4], kfB[4];
  half4 v0A[4], v1A[4], v0B[4], v1B[4];

  LOADG(kfA, v0A, v1A, 0);
  for (int g = 0; g < 64; g += 2) {               // 64 groups x 64 keys = 4096
    LOADG(kfB, v0B, v1B, g + 1);
    COMPG(kfA, v0A, v1A);
    if (g + 2 < 64) LOADG(kfA, v0A, v1A, g + 2);
    COMPG(kfB, v0B, v1B);
  }

  float lA = lA0 + lA1, lB = lB0 + lB1;
  lA += __shfl_xor(lA, 16, 64); lA += __shfl_xor(lA, 32, 64);
  lB += __shfl_xor(lB, 16, 64); lB += __shfl_xor(lB, 32, 64);
  const float rA = 1.f / lA, rB = 1.f / lB;

  // o -> LDS [s 32][ch 264]: wave wv owns channels wv*32..+32
  {
    const int chA = wv * 32 + quad * 4;
    half4 hA0 = { (_Float16)(oA0[0] * rA), (_Float16)(oA0[1] * rA),
                  (_Float16)(oA0[2] * rA), (_Float16)(oA0[3] * rA) };
    half4 hA1 = { (_Float16)(oA1[0] * rA), (_Float16)(oA1[1] * rA),
                  (_Float16)(oA1[2] * rA), (_Float16)(oA1[3] * rA) };
    half4 hB0 = { (_Float16)(oB0[0] * rB), (_Float16)(oB0[1] * rB),
                  (_Float16)(oB0[2] * rB), (_Float16)(oB0[3] * rB) };
    half4 hB1 = { (_Float16)(oB1[0] * rB), (_Float16)(oB1[1] * rB),
                  (_Float16)(oB1[2] * rB), (_Float16)(oB1[3] * rB) };
    *(half4*)&Lo[m * 264 + chA]            = hA0;
    *(half4*)&Lo[m * 264 + chA + 16]       = hA1;
    *(half4*)&Lo[(16 + m) * 264 + chA]     = hB0;
    *(half4*)&Lo[(16 + m) * 264 + chA + 16]= hB1;
  }
  __syncthreads();

  // ---- proj GEMM: 16 out-tiles across 8 waves (2 each), o from LDS
  const int mtb = wv * 2;
  const _Float16* wrow0 = wp + (size_t)((mtb + 0) * 16 + m) * C_DIM + quad * 8;
  const _Float16* wrow1 = wp + (size_t)((mtb + 1) * 16 + m) * C_DIM + quad * 8;
  floatx4 acc[2][2];
  acc[0][0] = (floatx4){0.f,0.f,0.f,0.f}; acc[0][1] = acc[0][0];
  acc[1][0] = acc[0][0]; acc[1][1] = acc[0][0];

  #pragma unroll
  for (int k0 = 0; k0 < C_DIM; k0 += 32) {
    half8 bf0 = *(const half8*)&Lo[m * 264 + k0 + quad * 8];
    half8 bf1 = *(const half8*)&Lo[(16 + m) * 264 + k0 + quad * 8];
    half8 af0 = *(const half8*)(wrow0 + k0);
    half8 af1 = *(const half8*)(wrow1 + k0);
    acc[0][0] = __builtin_amdgcn_mfma_f32_16x16x32_f16(af0, bf0, acc[0][0], 0, 0, 0);
    acc[0][1] = __builtin_amdgcn_mfma_f32_16x16x32_f16(af0, bf1, acc[0][1], 0, 0, 0);
    acc[1][0] = __builtin_amdgcn_mfma_f32_16x16x32_f16(af1, bf0, acc[1][0], 0, 0, 0);
    acc[1][1] = __builtin_amdgcn_mfma_f32_16x16x32_f16(af1, bf1, acc[1][1], 0, 0, 0);
  }
  #pragma unroll
  for (int j = 0; j < 2; ++j)
    #pragma unroll
    for (int sub = 0; sub < 2; ++sub) {
      int s = sbase + sub * 16 + m;
      #pragma unroll
      for (int r = 0; r < 4; ++r) {
        int c = (mtb + j) * 16 + quad * 4 + r;
        size_t idx = ((size_t)b * C_DIM + c) * S_LEN + s;
        out[idx] = x[idx] + acc[j][sub][r] + pbias[c];
      }
    }
}

// ---------------------------------------------------------------- launch
extern "C" void kernel_launch(void* const* d_in, const int* in_sizes, int n_in,
                              void* d_out, int out_size, void* d_ws, size_t ws_size,
                              hipStream_t stream) {
  const float* x        = (const float*)d_in[0];
  const float* gn_gamma = (const float*)d_in[1];
  const float* gn_beta  = (const float*)d_in[2];
  const float* qkv_w    = (const float*)d_in[3];
  const float* qkv_b    = (const float*)d_in[4];
  const float* proj_w   = (const float*)d_in[5];
  const float* proj_b   = (const float*)d_in[6];
  float* out = (float*)d_out;

  const size_t n1 = (size_t)2 * S_LEN * C_DIM;   // 2M elems = 4 MB f16
  char* ws = (char*)d_ws;
  _Float16* qx  = (_Float16*)ws;                 // (B,NH,S,hd)
  _Float16* kx  = qx + n1;                       // (B,NH,S,hd)
  _Float16* vx  = kx + n1;                       // (B,NH,hd,S)
  _Float16* wq  = vx + n1;                       // 768x256 f16
  _Float16* wp  = wq + 768 * 256;                // 256x256 f16
  float*    qbias = (float*)(wp + 256 * 256);    // 768 f32
  float*    pstat = qbias + 768;                 // 512*2 f32

  prep_stats<<<769, 256, 0, stream>>>(qkv_w, proj_w, qkv_b, x, wq, wp, qbias, pstat);
  qkv_gn_gemm<<<dim3(128, 2), 512, 0, stream>>>(wq, qbias, x, gn_gamma, gn_beta, pstat, qx, kx, vx);
  attn_proj<<<dim3(128, 2), 512, 0, stream>>>(qx, kx, vx, wp, proj_b, x, out);
}

// Round 10
// 168.381 us; speedup vs baseline: 2.2623x; 1.4045x over previous
//
#include <hip/hip_runtime.h>
#include <cstddef>

#define S_LEN 4096
#define C_DIM 256
#define NHEADS 8
#define HDIM 32

typedef __attribute__((ext_vector_type(8))) _Float16 half8;
typedef __attribute__((ext_vector_type(4))) _Float16 half4;
typedef __attribute__((ext_vector_type(2))) _Float16 h2t;
typedef __attribute__((ext_vector_type(2))) __fp16 fp16x2;
typedef __attribute__((ext_vector_type(4))) float floatx4;
typedef __attribute__((ext_vector_type(16))) float floatx16;

// scale * log2(e) folded into W_q and bias_q at prep time
#define SC2F ((float)(0.17677669529663687 * 1.4426950408889634))

// ---------------------------------------------------------------- prep + GN partial stats
__global__ __launch_bounds__(256) void prep_stats(
    const float* __restrict__ qkv_w, const float* __restrict__ proj_w,
    const float* __restrict__ qkv_b, const float* __restrict__ x,
    _Float16* __restrict__ wq, _Float16* __restrict__ wp,
    float* __restrict__ qbias, float* __restrict__ pstat)
{
  const int blk = blockIdx.x;
  const int tid = threadIdx.x;
  if (blk < 512) {
    __shared__ float red[2][4];
    const int gb = blk >> 3, e = blk & 7;       // gb = b*32+g
    const int g = gb & 31, b = gb >> 5;
    const float* xb = x + ((size_t)b * C_DIM + g * 8) * S_LEN + e * 4096;
    const float4* x4 = (const float4*)xb;       // 1024 float4
    float sum = 0.f, sumsq = 0.f;
    #pragma unroll
    for (int i = 0; i < 4; ++i) {
      float4 v = x4[tid + i * 256];
      sum += v.x + v.y + v.z + v.w;
      sumsq += v.x * v.x + v.y * v.y + v.z * v.z + v.w * v.w;
    }
    for (int off = 1; off < 64; off <<= 1) {
      sum += __shfl_xor(sum, off, 64);
      sumsq += __shfl_xor(sumsq, off, 64);
    }
    const int wv = tid >> 6, lane = tid & 63;
    if (lane == 0) { red[0][wv] = sum; red[1][wv] = sumsq; }
    __syncthreads();
    if (tid == 0) {
      pstat[(gb * 8 + e) * 2 + 0] = red[0][0] + red[0][1] + red[0][2] + red[0][3];
      pstat[(gb * 8 + e) * 2 + 1] = red[1][0] + red[1][1] + red[1][2] + red[1][3];
    }
  } else if (blk < 704) {
    // Wq: 192 blocks x 1024 elems (float4 per thread)
    const int i = (blk - 512) * 1024 + tid * 4;
    float4 v = *(const float4*)(qkv_w + i);
    const float sc = (i < 65536) ? SC2F : 1.f;   // q rows (first 256x256)
    half4 h = { (_Float16)(v.x * sc), (_Float16)(v.y * sc),
                (_Float16)(v.z * sc), (_Float16)(v.w * sc) };
    *(half4*)(wq + i) = h;
  } else if (blk < 768) {
    // Wp: 64 blocks x 1024 elems
    const int i = (blk - 704) * 1024 + tid * 4;
    float4 v = *(const float4*)(proj_w + i);
    half4 h = { (_Float16)v.x, (_Float16)v.y, (_Float16)v.z, (_Float16)v.w };
    *(half4*)(wp + i) = h;
  } else {
    // bias: 768 values
    #pragma unroll
    for (int j = 0; j < 3; ++j) {
      const int i = tid + j * 256;
      float bv = qkv_b[i];
      if (i < 256) bv *= SC2F;
      qbias[i] = bv;
    }
  }
}

// ---------------------------------------------------------------- QKV GEMM + inline GN
// R7 state (unchanged): one block = all 768 out rows for a 32-s slice;
// x read exactly once with GN applied during LDS stage.
__global__ __launch_bounds__(512) void qkv_gn_gemm(
    const _Float16* __restrict__ W, const float* __restrict__ bias,
    const float* __restrict__ x, const float* __restrict__ gamma,
    const float* __restrict__ beta, const float* __restrict__ pstat,
    _Float16* __restrict__ qo, _Float16* __restrict__ ko_,
    _Float16* __restrict__ vo)
{
  __shared__ __align__(16) _Float16 Ld[256 * 40];
  const int tid = threadIdx.x;
  const int b = blockIdx.y;
  const int s0 = blockIdx.x * 32;

  {  // ---- inline GN apply: x (c,s) f32 -> Ld[s][c] f16 (stride 264)
    const int c0 = (tid & 127) * 2, c1 = c0 + 1;
    const int sh = tid >> 7;                       // 0..3, 8 s each
    const int gb = b * 32 + (c0 >> 3);
    float s = 0.f, sq = 0.f;
    #pragma unroll
    for (int e = 0; e < 8; ++e) {
      s  += pstat[(gb * 8 + e) * 2 + 0];
      sq += pstat[(gb * 8 + e) * 2 + 1];
    }
    const float mean = s * (1.f / 32768.f);
    const float rstd = rsqrtf(sq * (1.f / 32768.f) - mean * mean + 1e-6f);
    const float ga0 = gamma[c0] * rstd, be0 = beta[c0] - mean * ga0;
    const float ga1 = gamma[c1] * rstd, be1 = beta[c1] - mean * ga1;
    const float4* xa = (const float4*)(x + ((size_t)b * C_DIM + c0) * S_LEN + s0 + sh * 8);
    const float4* xc = (const float4*)(x + ((size_t)b * C_DIM + c1) * S_LEN + s0 + sh * 8);
    #pragma unroll
    for (int j = 0; j < 2; ++j) {
      float4 a = xa[j], c = xc[j];
      int sl = sh * 8 + j * 4;
      *(h2t*)&Ld[(sl + 0) * 264 + c0] = (h2t){ (_Float16)(a.x * ga0 + be0), (_Float16)(c.x * ga1 + be1) };
      *(h2t*)&Ld[(sl + 1) * 264 + c0] = (h2t){ (_Float16)(a.y * ga0 + be0), (_Float16)(c.y * ga1 + be1) };
      *(h2t*)&Ld[(sl + 2) * 264 + c0] = (h2t){ (_Float16)(a.z * ga0 + be0), (_Float16)(c.z * ga1 + be1) };
      *(h2t*)&Ld[(sl + 3) * 264 + c0] = (h2t){ (_Float16)(a.w * ga0 + be0), (_Float16)(c.w * ga1 + be1) };
    }
  }
  __syncthreads();

  const int lane = tid & 63, wv = tid >> 6;       // 8 waves
  const int m = lane & 15, quad = lane >> 4;
  const _Float16* wrow[6];
  #pragma unroll
  for (int j = 0; j < 6; ++j)
    wrow[j] = W + (size_t)((wv + 8 * j) * 16 + m) * C_DIM + quad * 8;
  const _Float16* lp = &Ld[m * 264 + quad * 8];

  floatx4 acc[6][2];
  #pragma unroll
  for (int j = 0; j < 6; ++j) {
    acc[j][0] = (floatx4){0.f,0.f,0.f,0.f};
    acc[j][1] = (floatx4){0.f,0.f,0.f,0.f};
  }

  #pragma unroll 2
  for (int k0 = 0; k0 < C_DIM; k0 += 32) {
    half8 b0 = *(const half8*)(lp + k0);
    half8 b1 = *(const half8*)(lp + 16 * 264 + k0);
    #pragma unroll
    for (int j = 0; j < 6; ++j) {
      half8 a = *(const half8*)(wrow[j] + k0);
      acc[j][0] = __builtin_amdgcn_mfma_f32_16x16x32_f16(a, b0, acc[j][0], 0, 0, 0);
      acc[j][1] = __builtin_amdgcn_mfma_f32_16x16x32_f16(a, b1, acc[j][1], 0, 0, 0);
    }
  }

  __syncthreads();
  #pragma unroll
  for (int j = 0; j < 4; ++j) {
    const int ob = (wv + 8 * j) * 16 + quad * 4;  // 0..511
    const float bv0 = bias[ob], bv1 = bias[ob + 1],
                bv2 = bias[ob + 2], bv3 = bias[ob + 3];
    _Float16* dst = (ob < 256) ? qo : ko_;
    const int oo = ob & 255, n = oo >> 5, d0 = oo & 31;
    #pragma unroll
    for (int sub = 0; sub < 2; ++sub) {
      int s = s0 + sub * 16 + m;
      half4 h = { (_Float16)(acc[j][sub][0] + bv0), (_Float16)(acc[j][sub][1] + bv1),
                  (_Float16)(acc[j][sub][2] + bv2), (_Float16)(acc[j][sub][3] + bv3) };
      *(half4*)(dst + (((size_t)b * NHEADS + n) * S_LEN + s) * HDIM + d0) = h;
    }
  }
  _Float16* VLd = Ld;
  #pragma unroll
  for (int j = 4; j < 6; ++j) {
    const int ob = (wv + 8 * j) * 16 + quad * 4;  // 512..767
    const int lch = ob - 512;
    const float bv0 = bias[ob], bv1 = bias[ob + 1],
                bv2 = bias[ob + 2], bv3 = bias[ob + 3];
    #pragma unroll
    for (int sub = 0; sub < 2; ++sub) {
      int s = sub * 16 + m;
      VLd[(lch + 0) * 40 + s] = (_Float16)(acc[j][sub][0] + bv0);
      VLd[(lch + 1) * 40 + s] = (_Float16)(acc[j][sub][1] + bv1);
      VLd[(lch + 2) * 40 + s] = (_Float16)(acc[j][sub][2] + bv2);
      VLd[(lch + 3) * 40 + s] = (_Float16)(acc[j][sub][3] + bv3);
    }
  }
  __syncthreads();
  {
    const int ch = tid >> 1, sh = tid & 1;
    const int n = ch >> 5, d = ch & 31;
    _Float16* dst = vo + ((size_t)(b * NHEADS + n) * HDIM + d) * S_LEN + s0 + sh * 16;
    const _Float16* src = VLd + ch * 40 + sh * 16;
    *(half8*)(dst + 0) = *(const half8*)(src + 0);
    *(half8*)(dst + 8) = *(const half8*)(src + 8);
  }
}

// ---------------------------------------------------------------- Attention
// R10: 32x32x16 MFMA rewrite. Per 32 keys: 2 QK MFMA + 2 PV MFMA (was 12
// 16x16 MFMAs) + 4 permlane32_swap to map QK D-layout -> PV B-frag.
// QK D: col=lane&31=q, row(key)=(reg&3)+8*(reg>>2)+4*(lane>>5) [guide-verified].
// A/B frags: k = 8*(lane>>5)+j contiguous (proven for 16x16x32 by working code).
// Swaps pair lanes L<->L+32 (same q). K LDS stride 40->36 (2-way banks).
__global__ __launch_bounds__(512, 2) void attn_kernel(
    const _Float16* __restrict__ q, const _Float16* __restrict__ k,
    const _Float16* __restrict__ v, _Float16* __restrict__ o)
{
  __shared__ __align__(16) _Float16 Kl[2][128 * 36];  // (kk, d) stride 36
  __shared__ __align__(16) _Float16 Vl[2][32 * 136];  // (d, kk) stride 136
  const int tid = threadIdx.x;
  const int lane = tid & 63, wv = tid >> 6;          // wv 0..7
  const int l31 = lane & 31, hi = lane >> 5;
  const int n = blockIdx.y, b = blockIdx.z;
  const int qc = blockIdx.x;
  const int q0 = qc * 256 + wv * 32;
  const int bh = b * NHEADS + n;

  const _Float16* qb = q + (size_t)bh * S_LEN * HDIM;
  const _Float16* kb = k + (size_t)bh * S_LEN * HDIM;
  const _Float16* vb = v + (size_t)bh * HDIM * S_LEN;

  // Q B-frags: col q=l31, d = 8*hi+j (+16)
  half8 qf1 = *(const half8*)(qb + (size_t)(q0 + l31) * HDIM + hi * 8);
  half8 qf2 = *(const half8*)(qb + (size_t)(q0 + l31) * HDIM + 16 + hi * 8);

  // staging: wave wv stages K rows [wv*16,+16), V d-rows [wv*4,+4); 16B/lane
  const int krow = wv * 16 + (lane >> 2), kc = (lane & 3) * 8;
  const int vrow = wv * 4 + (lane >> 4), vc = (lane & 15) * 8;
  const _Float16* kg = kb + (size_t)krow * HDIM + kc;
  const _Float16* vg = vb + (size_t)vrow * S_LEN + vc;
  const int klds = krow * 36 + kc;
  const int vlds = vrow * 136 + vc;

  int4 kreg = *(const int4*)kg;
  int4 vreg = *(const int4*)vg;
  const _Float16* kgp = kg + 128 * HDIM;
  const _Float16* vgp = vg + 128;

  floatx16 oacc;
  #pragma unroll
  for (int i = 0; i < 16; ++i) oacc[i] = 0.f;
  float l0 = 0.f, l1 = 0.f;
  const fp16x2 one2 = { (__fp16)1.0f, (__fp16)1.0f };

  #pragma unroll 2
  for (int it = 0; it < 32; ++it) {          // 32 x 128 keys = 4096 (all)
    const int bufi = it & 1;
    *(int4*)(&Kl[bufi][klds]) = kreg;
    *(int4*)(&Vl[bufi][vlds]) = vreg;
    kreg = *(const int4*)kgp; kgp += 128 * HDIM;   // unconditional prefetch
    vreg = *(const int4*)vgp; vgp += 128;
    __syncthreads();
    const _Float16* Kb = Kl[bufi];
    const _Float16* Vb = Vl[bufi];

    #pragma unroll
    for (int t = 0; t < 4; ++t) {
      const int tt = (t + wv) & 3;           // per-wave phase rotation
      const int k32 = tt * 32;
      half8 kf1 = *(const half8*)(Kb + (k32 + l31) * 36 + hi * 8);
      half8 kf2 = *(const half8*)(Kb + (k32 + l31) * 36 + 16 + hi * 8);
      half8 vf1 = *(const half8*)(Vb + l31 * 136 + k32 + hi * 8);
      half8 vf2 = *(const half8*)(Vb + l31 * 136 + k32 + 16 + hi * 8);

      floatx16 sD;
      #pragma unroll
      for (int i = 0; i < 16; ++i) sD[i] = 0.f;
      __builtin_amdgcn_s_setprio(1);
      sD = __builtin_amdgcn_mfma_f32_32x32x16_f16(kf1, qf1, sD, 0, 0, 0);
      sD = __builtin_amdgcn_mfma_f32_32x32x16_f16(kf2, qf2, sD, 0, 0, 0);
      __builtin_amdgcn_s_setprio(0);

      // exp2 + pack: g[i] = pk(e[2i], e[2i+1]); k(g[i]) per layout above
      int g[8];
      #pragma unroll
      for (int i = 0; i < 8; ++i) {
        float e0 = __builtin_amdgcn_exp2f(sD[2 * i]);
        float e1 = __builtin_amdgcn_exp2f(sD[2 * i + 1]);
        fp16x2 p = __builtin_amdgcn_cvt_pkrtz(e0, e1);
        g[i] = __builtin_bit_cast(int, p);
      }
      // l accumulation (before swaps; all 16 values belong to q=l31)
      l0 = __builtin_amdgcn_fdot2(__builtin_bit_cast(fp16x2, g[0]), one2, l0, false);
      l0 = __builtin_amdgcn_fdot2(__builtin_bit_cast(fp16x2, g[1]), one2, l0, false);
      l0 = __builtin_amdgcn_fdot2(__builtin_bit_cast(fp16x2, g[2]), one2, l0, false);
      l0 = __builtin_amdgcn_fdot2(__builtin_bit_cast(fp16x2, g[3]), one2, l0, false);
      l1 = __builtin_amdgcn_fdot2(__builtin_bit_cast(fp16x2, g[4]), one2, l1, false);
      l1 = __builtin_amdgcn_fdot2(__builtin_bit_cast(fp16x2, g[5]), one2, l1, false);
      l1 = __builtin_amdgcn_fdot2(__builtin_bit_cast(fp16x2, g[6]), one2, l1, false);
      l1 = __builtin_amdgcn_fdot2(__builtin_bit_cast(fp16x2, g[7]), one2, l1, false);

      // B-frag rearrange: (w0,w2)=swap(g0,g2), (w1,w3)=swap(g1,g3), etc.
      // v_permlane32_swap_b32 D,S: D'=[D.lo,S.lo], S'=[D.hi,S.hi]
      asm volatile("v_permlane32_swap_b32 %0, %1" : "+v"(g[0]), "+v"(g[2]));
      asm volatile("v_permlane32_swap_b32 %0, %1" : "+v"(g[1]), "+v"(g[3]));
      asm volatile("v_permlane32_swap_b32 %0, %1" : "+v"(g[4]), "+v"(g[6]));
      asm volatile("v_permlane32_swap_b32 %0, %1" : "+v"(g[5]), "+v"(g[7]));
      union { half8 h; int u[4]; } B1, B2;
      B1.u[0] = g[0]; B1.u[1] = g[1]; B1.u[2] = g[2]; B1.u[3] = g[3];
      B2.u[0] = g[4]; B2.u[1] = g[5]; B2.u[2] = g[6]; B2.u[3] = g[7];

      __builtin_amdgcn_s_setprio(1);
      oacc = __builtin_amdgcn_mfma_f32_32x32x16_f16(vf1, B1.h, oacc, 0, 0, 0);
      oacc = __builtin_amdgcn_mfma_f32_32x32x16_f16(vf2, B2.h, oacc, 0, 0, 0);
      __builtin_amdgcn_s_setprio(0);
    }
  }
  float l = l0 + l1;
  l += __shfl_xor(l, 32, 64);
  const float r = 1.f / l;
  // oacc reg rr: d = (rr&3) + 8*(rr>>2) + 4*hi, q = l31
  _Float16* oh = o + ((size_t)bh * S_LEN + q0 + l31) * HDIM + hi * 4;
  #pragma unroll
  for (int t2 = 0; t2 < 4; ++t2) {
    half4 h = { (_Float16)(oacc[4 * t2 + 0] * r), (_Float16)(oacc[4 * t2 + 1] * r),
                (_Float16)(oacc[4 * t2 + 2] * r), (_Float16)(oacc[4 * t2 + 3] * r) };
    *(half4*)(oh + 8 * t2) = h;
  }
}

// ---------------------------------------------------------------- Proj GEMM
// R6 state (unchanged): plain GEMM on normalized o. Grid (2,64,2).
__global__ __launch_bounds__(256) void proj_gemm(
    const _Float16* __restrict__ W, const float* __restrict__ bias,
    const _Float16* __restrict__ o,
    const float* __restrict__ x, float* __restrict__ out)
{
  const int tid = threadIdx.x;
  const int lane = tid & 63, wv = tid >> 6;
  const int m = lane & 15, quad = lane >> 4;
  const int mtb = blockIdx.x * 8 + wv * 2;   // 2 mt tiles per wave
  const int s0 = blockIdx.y * 64;
  const int b = blockIdx.z;

  const _Float16* wrow0 = W + (size_t)((mtb + 0) * 16 + m) * C_DIM + quad * 8;
  const _Float16* wrow1 = W + (size_t)((mtb + 1) * 16 + m) * C_DIM + quad * 8;
  floatx4 acc[2][4];
  #pragma unroll
  for (int j = 0; j < 2; ++j)
    #pragma unroll
    for (int s = 0; s < 4; ++s) acc[j][s] = (floatx4){0.f,0.f,0.f,0.f};

  #pragma unroll
  for (int k0 = 0; k0 < C_DIM; k0 += 32) {
    const int n = k0 >> 5;
    const int d0 = quad * 8;
    half8 bf[4];
    #pragma unroll
    for (int sub = 0; sub < 4; ++sub) {
      size_t idx = (((size_t)(b * NHEADS + n)) * S_LEN + s0 + sub * 16 + m) * HDIM + d0;
      bf[sub] = *(const half8*)(o + idx);
    }
    half8 af0 = *(const half8*)(wrow0 + k0);
    half8 af1 = *(const half8*)(wrow1 + k0);
    #pragma unroll
    for (int sub = 0; sub < 4; ++sub) {
      acc[0][sub] = __builtin_amdgcn_mfma_f32_16x16x32_f16(af0, bf[sub], acc[0][sub], 0, 0, 0);
      acc[1][sub] = __builtin_amdgcn_mfma_f32_16x16x32_f16(af1, bf[sub], acc[1][sub], 0, 0, 0);
    }
  }
  #pragma unroll
  for (int j = 0; j < 2; ++j)
    #pragma unroll
    for (int sub = 0; sub < 4; ++sub) {
      int s = s0 + sub * 16 + m;
      #pragma unroll
      for (int r = 0; r < 4; ++r) {
        int c = (mtb + j) * 16 + quad * 4 + r;
        size_t idx = ((size_t)b * C_DIM + c) * S_LEN + s;
        out[idx] = x[idx] + acc[j][sub][r] + bias[c];
      }
    }
}

// ---------------------------------------------------------------- launch
extern "C" void kernel_launch(void* const* d_in, const int* in_sizes, int n_in,
                              void* d_out, int out_size, void* d_ws, size_t ws_size,
                              hipStream_t stream) {
  const float* x        = (const float*)d_in[0];
  const float* gn_gamma = (const float*)d_in[1];
  const float* gn_beta  = (const float*)d_in[2];
  const float* qkv_w    = (const float*)d_in[3];
  const float* qkv_b    = (const float*)d_in[4];
  const float* proj_w   = (const float*)d_in[5];
  const float* proj_b   = (const float*)d_in[6];
  float* out = (float*)d_out;

  const size_t n1 = (size_t)2 * S_LEN * C_DIM;   // 2M elems = 4 MB f16
  char* ws = (char*)d_ws;
  _Float16* qx  = (_Float16*)ws;                 // (B,NH,S,hd)
  _Float16* kx  = qx + n1;                       // (B,NH,S,hd)
  _Float16* vx  = kx + n1;                       // (B,NH,hd,S)
  _Float16* wq  = vx + n1;                       // 768x256 f16
  _Float16* wp  = wq + 768 * 256;                // 256x256 f16
  float*    qbias = (float*)(wp + 256 * 256);    // 768 f32
  float*    pstat = qbias + 768;                 // 512*2 f32
  _Float16* ox  = (_Float16*)(pstat + 1024);     // (B,NH,S,hd) f16 = 4 MB

  prep_stats<<<769, 256, 0, stream>>>(qkv_w, proj_w, qkv_b, x, wq, wp, qbias, pstat);
  qkv_gn_gemm<<<dim3(128, 2), 512, 0, stream>>>(wq, qbias, x, gn_gamma, gn_beta, pstat, qx, kx, vx);
  attn_kernel<<<dim3(16, 8, 2), 512, 0, stream>>>(qx, kx, vx, ox);
  proj_gemm<<<dim3(2, 64, 2), 256, 0, stream>>>(wp, proj_b, ox, x, out);
}

// Round 11
// 145.650 us; speedup vs baseline: 2.6153x; 1.1561x over previous
//
#include <hip/hip_runtime.h>
#include <cstddef>

#define S_LEN 4096
#define C_DIM 256
#define NHEADS 8
#define HDIM 32

typedef __attribute__((ext_vector_type(8))) _Float16 half8;
typedef __attribute__((ext_vector_type(4))) _Float16 half4;
typedef __attribute__((ext_vector_type(2))) _Float16 h2t;
typedef __attribute__((ext_vector_type(2))) __fp16 fp16x2;
typedef __attribute__((ext_vector_type(4))) float floatx4;

// scale * log2(e) folded into W_q and bias_q at prep time
#define SC2F ((float)(0.17677669529663687 * 1.4426950408889634))

// ---------------------------------------------------------------- prep + GN partial stats
__global__ __launch_bounds__(256) void prep_stats(
    const float* __restrict__ qkv_w, const float* __restrict__ proj_w,
    const float* __restrict__ qkv_b, const float* __restrict__ x,
    _Float16* __restrict__ wq, _Float16* __restrict__ wp,
    float* __restrict__ qbias, float* __restrict__ pstat)
{
  const int blk = blockIdx.x;
  const int tid = threadIdx.x;
  if (blk < 512) {
    __shared__ float red[2][4];
    const int gb = blk >> 3, e = blk & 7;       // gb = b*32+g
    const int g = gb & 31, b = gb >> 5;
    const float* xb = x + ((size_t)b * C_DIM + g * 8) * S_LEN + e * 4096;
    const float4* x4 = (const float4*)xb;       // 1024 float4
    float sum = 0.f, sumsq = 0.f;
    #pragma unroll
    for (int i = 0; i < 4; ++i) {
      float4 v = x4[tid + i * 256];
      sum += v.x + v.y + v.z + v.w;
      sumsq += v.x * v.x + v.y * v.y + v.z * v.z + v.w * v.w;
    }
    for (int off = 1; off < 64; off <<= 1) {
      sum += __shfl_xor(sum, off, 64);
      sumsq += __shfl_xor(sumsq, off, 64);
    }
    const int wv = tid >> 6, lane = tid & 63;
    if (lane == 0) { red[0][wv] = sum; red[1][wv] = sumsq; }
    __syncthreads();
    if (tid == 0) {
      pstat[(gb * 8 + e) * 2 + 0] = red[0][0] + red[0][1] + red[0][2] + red[0][3];
      pstat[(gb * 8 + e) * 2 + 1] = red[1][0] + red[1][1] + red[1][2] + red[1][3];
    }
  } else if (blk < 704) {
    // Wq: 192 blocks x 1024 elems (float4 per thread)
    const int i = (blk - 512) * 1024 + tid * 4;
    float4 v = *(const float4*)(qkv_w + i);
    const float sc = (i < 65536) ? SC2F : 1.f;   // q rows (first 256x256)
    half4 h = { (_Float16)(v.x * sc), (_Float16)(v.y * sc),
                (_Float16)(v.z * sc), (_Float16)(v.w * sc) };
    *(half4*)(wq + i) = h;
  } else if (blk < 768) {
    // Wp: 64 blocks x 1024 elems
    const int i = (blk - 704) * 1024 + tid * 4;
    float4 v = *(const float4*)(proj_w + i);
    half4 h = { (_Float16)v.x, (_Float16)v.y, (_Float16)v.z, (_Float16)v.w };
    *(half4*)(wp + i) = h;
  } else {
    // bias: 768 values
    #pragma unroll
    for (int j = 0; j < 3; ++j) {
      const int i = tid + j * 256;
      float bv = qkv_b[i];
      if (i < 256) bv *= SC2F;
      qbias[i] = bv;
    }
  }
}

// ---------------------------------------------------------------- QKV GEMM + inline GN
// R7 state (unchanged): one block = all 768 out rows for a 32-s slice;
// x read exactly once with GN applied during LDS stage.
__global__ __launch_bounds__(512) void qkv_gn_gemm(
    const _Float16* __restrict__ W, const float* __restrict__ bias,
    const float* __restrict__ x, const float* __restrict__ gamma,
    const float* __restrict__ beta, const float* __restrict__ pstat,
    _Float16* __restrict__ qo, _Float16* __restrict__ ko_,
    _Float16* __restrict__ vo)
{
  __shared__ __align__(16) _Float16 Ld[256 * 40];
  const int tid = threadIdx.x;
  const int b = blockIdx.y;
  const int s0 = blockIdx.x * 32;

  {  // ---- inline GN apply: x (c,s) f32 -> Ld[s][c] f16 (stride 264)
    const int c0 = (tid & 127) * 2, c1 = c0 + 1;
    const int sh = tid >> 7;                       // 0..3, 8 s each
    const int gb = b * 32 + (c0 >> 3);
    float s = 0.f, sq = 0.f;
    #pragma unroll
    for (int e = 0; e < 8; ++e) {
      s  += pstat[(gb * 8 + e) * 2 + 0];
      sq += pstat[(gb * 8 + e) * 2 + 1];
    }
    const float mean = s * (1.f / 32768.f);
    const float rstd = rsqrtf(sq * (1.f / 32768.f) - mean * mean + 1e-6f);
    const float ga0 = gamma[c0] * rstd, be0 = beta[c0] - mean * ga0;
    const float ga1 = gamma[c1] * rstd, be1 = beta[c1] - mean * ga1;
    const float4* xa = (const float4*)(x + ((size_t)b * C_DIM + c0) * S_LEN + s0 + sh * 8);
    const float4* xc = (const float4*)(x + ((size_t)b * C_DIM + c1) * S_LEN + s0 + sh * 8);
    #pragma unroll
    for (int j = 0; j < 2; ++j) {
      float4 a = xa[j], c = xc[j];
      int sl = sh * 8 + j * 4;
      *(h2t*)&Ld[(sl + 0) * 264 + c0] = (h2t){ (_Float16)(a.x * ga0 + be0), (_Float16)(c.x * ga1 + be1) };
      *(h2t*)&Ld[(sl + 1) * 264 + c0] = (h2t){ (_Float16)(a.y * ga0 + be0), (_Float16)(c.y * ga1 + be1) };
      *(h2t*)&Ld[(sl + 2) * 264 + c0] = (h2t){ (_Float16)(a.z * ga0 + be0), (_Float16)(c.z * ga1 + be1) };
      *(h2t*)&Ld[(sl + 3) * 264 + c0] = (h2t){ (_Float16)(a.w * ga0 + be0), (_Float16)(c.w * ga1 + be1) };
    }
  }
  __syncthreads();

  const int lane = tid & 63, wv = tid >> 6;       // 8 waves
  const int m = lane & 15, quad = lane >> 4;
  const _Float16* wrow[6];
  #pragma unroll
  for (int j = 0; j < 6; ++j)
    wrow[j] = W + (size_t)((wv + 8 * j) * 16 + m) * C_DIM + quad * 8;
  const _Float16* lp = &Ld[m * 264 + quad * 8];

  floatx4 acc[6][2];
  #pragma unroll
  for (int j = 0; j < 6; ++j) {
    acc[j][0] = (floatx4){0.f,0.f,0.f,0.f};
    acc[j][1] = (floatx4){0.f,0.f,0.f,0.f};
  }

  #pragma unroll 2
  for (int k0 = 0; k0 < C_DIM; k0 += 32) {
    half8 b0 = *(const half8*)(lp + k0);
    half8 b1 = *(const half8*)(lp + 16 * 264 + k0);
    #pragma unroll
    for (int j = 0; j < 6; ++j) {
      half8 a = *(const half8*)(wrow[j] + k0);
      acc[j][0] = __builtin_amdgcn_mfma_f32_16x16x32_f16(a, b0, acc[j][0], 0, 0, 0);
      acc[j][1] = __builtin_amdgcn_mfma_f32_16x16x32_f16(a, b1, acc[j][1], 0, 0, 0);
    }
  }

  __syncthreads();
  #pragma unroll
  for (int j = 0; j < 4; ++j) {
    const int ob = (wv + 8 * j) * 16 + quad * 4;  // 0..511
    const float bv0 = bias[ob], bv1 = bias[ob + 1],
                bv2 = bias[ob + 2], bv3 = bias[ob + 3];
    _Float16* dst = (ob < 256) ? qo : ko_;
    const int oo = ob & 255, n = oo >> 5, d0 = oo & 31;
    #pragma unroll
    for (int sub = 0; sub < 2; ++sub) {
      int s = s0 + sub * 16 + m;
      half4 h = { (_Float16)(acc[j][sub][0] + bv0), (_Float16)(acc[j][sub][1] + bv1),
                  (_Float16)(acc[j][sub][2] + bv2), (_Float16)(acc[j][sub][3] + bv3) };
      *(half4*)(dst + (((size_t)b * NHEADS + n) * S_LEN + s) * HDIM + d0) = h;
    }
  }
  _Float16* VLd = Ld;
  #pragma unroll
  for (int j = 4; j < 6; ++j) {
    const int ob = (wv + 8 * j) * 16 + quad * 4;  // 512..767
    const int lch = ob - 512;
    const float bv0 = bias[ob], bv1 = bias[ob + 1],
                bv2 = bias[ob + 2], bv3 = bias[ob + 3];
    #pragma unroll
    for (int sub = 0; sub < 2; ++sub) {
      int s = sub * 16 + m;
      VLd[(lch + 0) * 40 + s] = (_Float16)(acc[j][sub][0] + bv0);
      VLd[(lch + 1) * 40 + s] = (_Float16)(acc[j][sub][1] + bv1);
      VLd[(lch + 2) * 40 + s] = (_Float16)(acc[j][sub][2] + bv2);
      VLd[(lch + 3) * 40 + s] = (_Float16)(acc[j][sub][3] + bv3);
    }
  }
  __syncthreads();
  {
    const int ch = tid >> 1, sh = tid & 1;
    const int n = ch >> 5, d = ch & 31;
    _Float16* dst = vo + ((size_t)(b * NHEADS + n) * HDIM + d) * S_LEN + s0 + sh * 16;
    const _Float16* src = VLd + ch * 40 + sh * 16;
    *(half8*)(dst + 0) = *(const half8*)(src + 0);
    *(half8*)(dst + 8) = *(const half8*)(src + 8);
  }
}

// softmax/PV inner body shared by both attn variants (16-key sub-step)
#define ATTN_STEP(KF, VF0, VF1)                                            \
  do {                                                                     \
    __builtin_amdgcn_s_setprio(1);                                         \
    floatx4 sA = __builtin_amdgcn_mfma_f32_16x16x32_f16(KF, qfA, zz, 0, 0, 0); \
    floatx4 sB = __builtin_amdgcn_mfma_f32_16x16x32_f16(KF, qfB, zz, 0, 0, 0); \
    __builtin_amdgcn_s_setprio(0);                                         \
    float eA0 = __builtin_amdgcn_exp2f(sA[0]);                             \
    float eA1 = __builtin_amdgcn_exp2f(sA[1]);                             \
    float eA2 = __builtin_amdgcn_exp2f(sA[2]);                             \
    float eA3 = __builtin_amdgcn_exp2f(sA[3]);                             \
    float eB0 = __builtin_amdgcn_exp2f(sB[0]);                             \
    float eB1 = __builtin_amdgcn_exp2f(sB[1]);                             \
    float eB2 = __builtin_amdgcn_exp2f(sB[2]);                             \
    float eB3 = __builtin_amdgcn_exp2f(sB[3]);                             \
    half4 pA, pB;                                                          \
    fp16x2 pAlo = __builtin_amdgcn_cvt_pkrtz(eA0, eA1);                    \
    fp16x2 pAhi = __builtin_amdgcn_cvt_pkrtz(eA2, eA3);                    \
    fp16x2 pBlo = __builtin_amdgcn_cvt_pkrtz(eB0, eB1);                    \
    fp16x2 pBhi = __builtin_amdgcn_cvt_pkrtz(eB2, eB3);                    \
    *(fp16x2*)&pA = pAlo; *((fp16x2*)&pA + 1) = pAhi;                      \
    *(fp16x2*)&pB = pBlo; *((fp16x2*)&pB + 1) = pBhi;                      \
    lA0 = __builtin_amdgcn_fdot2(pAlo, one2, lA0, false);                  \
    lA1 = __builtin_amdgcn_fdot2(pAhi, one2, lA1, false);                  \
    lB0 = __builtin_amdgcn_fdot2(pBlo, one2, lB0, false);                  \
    lB1 = __builtin_amdgcn_fdot2(pBhi, one2, lB1, false);                  \
    __builtin_amdgcn_s_setprio(1);                                         \
    oA0 = __builtin_amdgcn_mfma_f32_16x16x16f16(VF0, pA, oA0, 0, 0, 0);    \
    oA1 = __builtin_amdgcn_mfma_f32_16x16x16f16(VF1, pA, oA1, 0, 0, 0);    \
    oB0 = __builtin_amdgcn_mfma_f32_16x16x16f16(VF0, pB, oB0, 0, 0, 0);    \
    oB1 = __builtin_amdgcn_mfma_f32_16x16x16f16(VF1, pB, oB1, 0, 0, 0);    \
    __builtin_amdgcn_s_setprio(0);                                         \
  } while (0)

#define ATTN_EPILOGUE                                                      \
  float lA = lA0 + lA1, lB = lB0 + lB1;                                    \
  lA += __shfl_xor(lA, 16, 64); lA += __shfl_xor(lA, 32, 64);              \
  lB += __shfl_xor(lB, 16, 64); lB += __shfl_xor(lB, 32, 64);              \
  const float rA = 1.f / lA, rB = 1.f / lB;                                \
  _Float16* obase = o + ((size_t)bh * S_LEN) * HDIM;                       \
  {                                                                        \
    _Float16* oh = obase + (size_t)(q0 + m) * HDIM;                        \
    half4 h0 = { (_Float16)(oA0[0] * rA), (_Float16)(oA0[1] * rA),         \
                 (_Float16)(oA0[2] * rA), (_Float16)(oA0[3] * rA) };       \
    half4 h1 = { (_Float16)(oA1[0] * rA), (_Float16)(oA1[1] * rA),         \
                 (_Float16)(oA1[2] * rA), (_Float16)(oA1[3] * rA) };       \
    *(half4*)(oh + quad * 4) = h0;                                         \
    *(half4*)(oh + 16 + quad * 4) = h1;                                    \
  }                                                                        \
  {                                                                        \
    _Float16* oh = obase + (size_t)(q0 + 16 + m) * HDIM;                   \
    half4 h0 = { (_Float16)(oB0[0] * rB), (_Float16)(oB0[1] * rB),         \
                 (_Float16)(oB0[2] * rB), (_Float16)(oB0[3] * rB) };       \
    half4 h1 = { (_Float16)(oB1[0] * rB), (_Float16)(oB1[1] * rB),         \
                 (_Float16)(oB1[2] * rB), (_Float16)(oB1[3] * rB) };       \
    *(half4*)(oh + quad * 4) = h0;                                         \
    *(half4*)(oh + 16 + quad * 4) = h1;                                    \
  }

// ---------------------------------------------------------------- Attention (256-key tiles)
// R11: 256-key K/V tiles via dynamic LDS (74752 B, needs
// hipFuncSetAttribute). Barriers 32 -> 16. Inner 16-key step identical to
// the proven R3/R7 body; per-wave phase rotation over 16 sub-steps.
__global__ __launch_bounds__(512) void attn_kernel256(
    const _Float16* __restrict__ q, const _Float16* __restrict__ k,
    const _Float16* __restrict__ v, _Float16* __restrict__ o)
{
  extern __shared__ __align__(16) _Float16 smem[];
  _Float16* Klb = smem;                 // [2][256*40] = 2x20480 B
  _Float16* Vlb = smem + 20480;         // [2][32*264] = 2x16896 B
  const int tid = threadIdx.x;
  const int lane = tid & 63, wv = tid >> 6;          // wv 0..7
  const int m = lane & 15, quad = lane >> 4;
  const int n = blockIdx.y, b = blockIdx.z;
  const int qc = blockIdx.x;
  const int q0 = qc * 256 + wv * 32;
  const int bh = b * NHEADS + n;

  const _Float16* qb = q + (size_t)bh * S_LEN * HDIM;
  const _Float16* kb = k + (size_t)bh * S_LEN * HDIM;
  const _Float16* vb = v + (size_t)bh * HDIM * S_LEN;

  half8 qfA = *(const half8*)(qb + (size_t)(q0 + m) * HDIM + quad * 8);
  half8 qfB = *(const half8*)(qb + (size_t)(q0 + 16 + m) * HDIM + quad * 8);

  // staging: wave wv stages K rows [wv*32,+32), V d-rows [wv*4,+4); 32B/lane
  const int krow = wv * 32 + (lane >> 1), kc = (lane & 1) * 16;
  const int vrow = wv * 4 + (lane >> 4), vc = (lane & 15) * 16;
  const _Float16* kg = kb + (size_t)krow * HDIM + kc;
  const _Float16* vg = vb + (size_t)vrow * S_LEN + vc;
  const int klds = krow * 40 + kc;
  const int vlds = vrow * 264 + vc;

  int4 kra = *(const int4*)kg, krb = *(const int4*)(kg + 8);
  int4 vra = *(const int4*)vg, vrb = *(const int4*)(vg + 8);
  const _Float16* kgp = kg + 256 * HDIM;
  const _Float16* vgp = vg + 256;

  floatx4 oA0 = {0.f,0.f,0.f,0.f}, oA1 = oA0, oB0 = oA0, oB1 = oA0;
  float lA0 = 0.f, lA1 = 0.f, lB0 = 0.f, lB1 = 0.f;
  const fp16x2 one2 = { (__fp16)1.0f, (__fp16)1.0f };
  const floatx4 zz = {0.f,0.f,0.f,0.f};

  #pragma unroll 2
  for (int it = 0; it < 16; ++it) {          // 16 x 256 keys = 4096 (all)
    const int bufi = it & 1;
    _Float16* Kl = Klb + bufi * 10240;
    _Float16* Vl = Vlb + bufi * 8448;
    *(int4*)(Kl + klds) = kra; *(int4*)(Kl + klds + 8) = krb;
    *(int4*)(Vl + vlds) = vra; *(int4*)(Vl + vlds + 8) = vrb;
    kra = *(const int4*)kgp; krb = *(const int4*)(kgp + 8);   // prefetch
    vra = *(const int4*)vgp; vrb = *(const int4*)(vgp + 8);
    kgp += 256 * HDIM; vgp += 256;
    __syncthreads();
    const _Float16* Kb = Kl;
    const _Float16* Vb = Vl;

    #pragma unroll
    for (int t = 0; t < 16; ++t) {
      const int tt = (t + wv * 2) & 15;      // per-wave phase rotation
      half8 kf  = *(const half8*)(Kb + (tt * 16 + m) * 40 + quad * 8);
      half4 vf0 = *(const half4*)(Vb + m * 264 + tt * 16 + quad * 4);
      half4 vf1 = *(const half4*)(Vb + (16 + m) * 264 + tt * 16 + quad * 4);
      ATTN_STEP(kf, vf0, vf1);
    }
  }
  ATTN_EPILOGUE
}

// ---------------------------------------------------------------- Attention (128-key fallback)
// R7 attn verbatim (static LDS); used if dynamic-LDS attribute fails.
__global__ __launch_bounds__(512) void attn_kernel128(
    const _Float16* __restrict__ q, const _Float16* __restrict__ k,
    const _Float16* __restrict__ v, _Float16* __restrict__ o)
{
  __shared__ __align__(16) _Float16 Kl[2][128 * 40];  // (kk, d) stride 40
  __shared__ __align__(16) _Float16 Vl[2][32 * 136];  // (d, kk) stride 136
  const int tid = threadIdx.x;
  const int lane = tid & 63, wv = tid >> 6;          // wv 0..7
  const int m = lane & 15, quad = lane >> 4;
  const int n = blockIdx.y, b = blockIdx.z;
  const int qc = blockIdx.x;
  const int q0 = qc * 256 + wv * 32;
  const int bh = b * NHEADS + n;

  const _Float16* qb = q + (size_t)bh * S_LEN * HDIM;
  const _Float16* kb = k + (size_t)bh * S_LEN * HDIM;
  const _Float16* vb = v + (size_t)bh * HDIM * S_LEN;

  half8 qfA = *(const half8*)(qb + (size_t)(q0 + m) * HDIM + quad * 8);
  half8 qfB = *(const half8*)(qb + (size_t)(q0 + 16 + m) * HDIM + quad * 8);

  const int krow = wv * 16 + (lane >> 2), kc = (lane & 3) * 8;
  const int vrow = wv * 4 + (lane >> 4), vc = (lane & 15) * 8;
  const _Float16* kg = kb + (size_t)krow * HDIM + kc;
  const _Float16* vg = vb + (size_t)vrow * S_LEN + vc;
  const int klds = krow * 40 + kc;
  const int vlds = vrow * 136 + vc;

  int4 kreg = *(const int4*)kg;
  int4 vreg = *(const int4*)vg;
  const _Float16* kgp = kg + 128 * HDIM;
  const _Float16* vgp = vg + 128;

  floatx4 oA0 = {0.f,0.f,0.f,0.f}, oA1 = oA0, oB0 = oA0, oB1 = oA0;
  float lA0 = 0.f, lA1 = 0.f, lB0 = 0.f, lB1 = 0.f;
  const fp16x2 one2 = { (__fp16)1.0f, (__fp16)1.0f };
  const floatx4 zz = {0.f,0.f,0.f,0.f};

  #pragma unroll 2
  for (int it = 0; it < 32; ++it) {          // 32 x 128 keys = 4096 (all)
    const int bufi = it & 1;
    *(int4*)(&Kl[bufi][klds]) = kreg;
    *(int4*)(&Vl[bufi][vlds]) = vreg;
    kreg = *(const int4*)kgp; kgp += 128 * HDIM;   // unconditional prefetch
    vreg = *(const int4*)vgp; vgp += 128;
    __syncthreads();
    const _Float16* Kb = Kl[bufi];
    const _Float16* Vb = Vl[bufi];

    #pragma unroll
    for (int t = 0; t < 8; ++t) {
      const int tt = (t + wv) & 7;           // per-wave phase rotation
      half8 kf  = *(const half8*)(Kb + (tt * 16 + m) * 40 + quad * 8);
      half4 vf0 = *(const half4*)(Vb + m * 136 + tt * 16 + quad * 4);
      half4 vf1 = *(const half4*)(Vb + (16 + m) * 136 + tt * 16 + quad * 4);
      ATTN_STEP(kf, vf0, vf1);
    }
  }
  ATTN_EPILOGUE
}

// ---------------------------------------------------------------- Proj GEMM
// R6 state (unchanged): plain GEMM on normalized o. Grid (2,64,2).
__global__ __launch_bounds__(256) void proj_gemm(
    const _Float16* __restrict__ W, const float* __restrict__ bias,
    const _Float16* __restrict__ o,
    const float* __restrict__ x, float* __restrict__ out)
{
  const int tid = threadIdx.x;
  const int lane = tid & 63, wv = tid >> 6;
  const int m = lane & 15, quad = lane >> 4;
  const int mtb = blockIdx.x * 8 + wv * 2;   // 2 mt tiles per wave
  const int s0 = blockIdx.y * 64;
  const int b = blockIdx.z;

  const _Float16* wrow0 = W + (size_t)((mtb + 0) * 16 + m) * C_DIM + quad * 8;
  const _Float16* wrow1 = W + (size_t)((mtb + 1) * 16 + m) * C_DIM + quad * 8;
  floatx4 acc[2][4];
  #pragma unroll
  for (int j = 0; j < 2; ++j)
    #pragma unroll
    for (int s = 0; s < 4; ++s) acc[j][s] = (floatx4){0.f,0.f,0.f,0.f};

  #pragma unroll
  for (int k0 = 0; k0 < C_DIM; k0 += 32) {
    const int n = k0 >> 5;
    const int d0 = quad * 8;
    half8 bf[4];
    #pragma unroll
    for (int sub = 0; sub < 4; ++sub) {
      size_t idx = (((size_t)(b * NHEADS + n)) * S_LEN + s0 + sub * 16 + m) * HDIM + d0;
      bf[sub] = *(const half8*)(o + idx);
    }
    half8 af0 = *(const half8*)(wrow0 + k0);
    half8 af1 = *(const half8*)(wrow1 + k0);
    #pragma unroll
    for (int sub = 0; sub < 4; ++sub) {
      acc[0][sub] = __builtin_amdgcn_mfma_f32_16x16x32_f16(af0, bf[sub], acc[0][sub], 0, 0, 0);
      acc[1][sub] = __builtin_amdgcn_mfma_f32_16x16x32_f16(af1, bf[sub], acc[1][sub], 0, 0, 0);
    }
  }
  #pragma unroll
  for (int j = 0; j < 2; ++j)
    #pragma unroll
    for (int sub = 0; sub < 4; ++sub) {
      int s = s0 + sub * 16 + m;
      #pragma unroll
      for (int r = 0; r < 4; ++r) {
        int c = (mtb + j) * 16 + quad * 4 + r;
        size_t idx = ((size_t)b * C_DIM + c) * S_LEN + s;
        out[idx] = x[idx] + acc[j][sub][r] + bias[c];
      }
    }
}

// ---------------------------------------------------------------- launch
extern "C" void kernel_launch(void* const* d_in, const int* in_sizes, int n_in,
                              void* d_out, int out_size, void* d_ws, size_t ws_size,
                              hipStream_t stream) {
  const float* x        = (const float*)d_in[0];
  const float* gn_gamma = (const float*)d_in[1];
  const float* gn_beta  = (const float*)d_in[2];
  const float* qkv_w    = (const float*)d_in[3];
  const float* qkv_b    = (const float*)d_in[4];
  const float* proj_w   = (const float*)d_in[5];
  const float* proj_b   = (const float*)d_in[6];
  float* out = (float*)d_out;

  const size_t n1 = (size_t)2 * S_LEN * C_DIM;   // 2M elems = 4 MB f16
  char* ws = (char*)d_ws;
  _Float16* qx  = (_Float16*)ws;                 // (B,NH,S,hd)
  _Float16* kx  = qx + n1;                       // (B,NH,S,hd)
  _Float16* vx  = kx + n1;                       // (B,NH,hd,S)
  _Float16* wq  = vx + n1;                       // 768x256 f16
  _Float16* wp  = wq + 768 * 256;                // 256x256 f16
  float*    qbias = (float*)(wp + 256 * 256);    // 768 f32
  float*    pstat = qbias + 768;                 // 512*2 f32
  _Float16* ox  = (_Float16*)(pstat + 1024);     // (B,NH,S,hd) f16 = 4 MB

  static int big_ok = -1;
  if (big_ok < 0) {
    big_ok = (hipFuncSetAttribute((const void*)attn_kernel256,
              hipFuncAttributeMaxDynamicSharedMemorySize, 74752) == hipSuccess)
             ? 1 : 0;
  }

  prep_stats<<<769, 256, 0, stream>>>(qkv_w, proj_w, qkv_b, x, wq, wp, qbias, pstat);
  qkv_gn_gemm<<<dim3(128, 2), 512, 0, stream>>>(wq, qbias, x, gn_gamma, gn_beta, pstat, qx, kx, vx);
  if (big_ok)
    attn_kernel256<<<dim3(16, 8, 2), 512, 74752, stream>>>(qx, kx, vx, ox);
  else
    attn_kernel128<<<dim3(16, 8, 2), 512, 0, stream>>>(qx, kx, vx, ox);
  proj_gemm<<<dim3(2, 64, 2), 256, 0, stream>>>(wp, proj_b, ox, x, out);
}

// Round 12
// 145.032 us; speedup vs baseline: 2.6265x; 1.0043x over previous
//
#include <hip/hip_runtime.h>
#include <cstddef>

#define S_LEN 4096
#define C_DIM 256
#define NHEADS 8
#define HDIM 32

typedef __attribute__((ext_vector_type(8))) _Float16 half8;
typedef __attribute__((ext_vector_type(4))) _Float16 half4;
typedef __attribute__((ext_vector_type(2))) _Float16 h2t;
typedef __attribute__((ext_vector_type(2))) __fp16 fp16x2;
typedef __attribute__((ext_vector_type(4))) float floatx4;

// scale * log2(e) folded into W_q and bias_q at prep time
#define SC2F ((float)(0.17677669529663687 * 1.4426950408889634))

// ---------------------------------------------------------------- prep + GN partial stats
__global__ __launch_bounds__(256) void prep_stats(
    const float* __restrict__ qkv_w, const float* __restrict__ proj_w,
    const float* __restrict__ qkv_b, const float* __restrict__ x,
    _Float16* __restrict__ wq, _Float16* __restrict__ wp,
    float* __restrict__ qbias, float* __restrict__ pstat)
{
  const int blk = blockIdx.x;
  const int tid = threadIdx.x;
  if (blk < 512) {
    __shared__ float red[2][4];
    const int gb = blk >> 3, e = blk & 7;       // gb = b*32+g
    const int g = gb & 31, b = gb >> 5;
    const float* xb = x + ((size_t)b * C_DIM + g * 8) * S_LEN + e * 4096;
    const float4* x4 = (const float4*)xb;       // 1024 float4
    float sum = 0.f, sumsq = 0.f;
    #pragma unroll
    for (int i = 0; i < 4; ++i) {
      float4 v = x4[tid + i * 256];
      sum += v.x + v.y + v.z + v.w;
      sumsq += v.x * v.x + v.y * v.y + v.z * v.z + v.w * v.w;
    }
    for (int off = 1; off < 64; off <<= 1) {
      sum += __shfl_xor(sum, off, 64);
      sumsq += __shfl_xor(sumsq, off, 64);
    }
    const int wv = tid >> 6, lane = tid & 63;
    if (lane == 0) { red[0][wv] = sum; red[1][wv] = sumsq; }
    __syncthreads();
    if (tid == 0) {
      pstat[(gb * 8 + e) * 2 + 0] = red[0][0] + red[0][1] + red[0][2] + red[0][3];
      pstat[(gb * 8 + e) * 2 + 1] = red[1][0] + red[1][1] + red[1][2] + red[1][3];
    }
  } else if (blk < 704) {
    // Wq: 192 blocks x 1024 elems (float4 per thread)
    const int i = (blk - 512) * 1024 + tid * 4;
    float4 v = *(const float4*)(qkv_w + i);
    const float sc = (i < 65536) ? SC2F : 1.f;   // q rows (first 256x256)
    half4 h = { (_Float16)(v.x * sc), (_Float16)(v.y * sc),
                (_Float16)(v.z * sc), (_Float16)(v.w * sc) };
    *(half4*)(wq + i) = h;
  } else if (blk < 768) {
    // Wp: 64 blocks x 1024 elems
    const int i = (blk - 704) * 1024 + tid * 4;
    float4 v = *(const float4*)(proj_w + i);
    half4 h = { (_Float16)v.x, (_Float16)v.y, (_Float16)v.z, (_Float16)v.w };
    *(half4*)(wp + i) = h;
  } else {
    // bias: 768 values
    #pragma unroll
    for (int j = 0; j < 3; ++j) {
      const int i = tid + j * 256;
      float bv = qkv_b[i];
      if (i < 256) bv *= SC2F;
      qbias[i] = bv;
    }
  }
}

// ---------------------------------------------------------------- QKV GEMM + inline GN
// R7 state (unchanged): one block = all 768 out rows for a 32-s slice;
// x read exactly once with GN applied during LDS stage.
__global__ __launch_bounds__(512) void qkv_gn_gemm(
    const _Float16* __restrict__ W, const float* __restrict__ bias,
    const float* __restrict__ x, const float* __restrict__ gamma,
    const float* __restrict__ beta, const float* __restrict__ pstat,
    _Float16* __restrict__ qo, _Float16* __restrict__ ko_,
    _Float16* __restrict__ vo)
{
  __shared__ __align__(16) _Float16 Ld[256 * 40];
  const int tid = threadIdx.x;
  const int b = blockIdx.y;
  const int s0 = blockIdx.x * 32;

  {  // ---- inline GN apply: x (c,s) f32 -> Ld[s][c] f16 (stride 264)
    const int c0 = (tid & 127) * 2, c1 = c0 + 1;
    const int sh = tid >> 7;                       // 0..3, 8 s each
    const int gb = b * 32 + (c0 >> 3);
    float s = 0.f, sq = 0.f;
    #pragma unroll
    for (int e = 0; e < 8; ++e) {
      s  += pstat[(gb * 8 + e) * 2 + 0];
      sq += pstat[(gb * 8 + e) * 2 + 1];
    }
    const float mean = s * (1.f / 32768.f);
    const float rstd = rsqrtf(sq * (1.f / 32768.f) - mean * mean + 1e-6f);
    const float ga0 = gamma[c0] * rstd, be0 = beta[c0] - mean * ga0;
    const float ga1 = gamma[c1] * rstd, be1 = beta[c1] - mean * ga1;
    const float4* xa = (const float4*)(x + ((size_t)b * C_DIM + c0) * S_LEN + s0 + sh * 8);
    const float4* xc = (const float4*)(x + ((size_t)b * C_DIM + c1) * S_LEN + s0 + sh * 8);
    #pragma unroll
    for (int j = 0; j < 2; ++j) {
      float4 a = xa[j], c = xc[j];
      int sl = sh * 8 + j * 4;
      *(h2t*)&Ld[(sl + 0) * 264 + c0] = (h2t){ (_Float16)(a.x * ga0 + be0), (_Float16)(c.x * ga1 + be1) };
      *(h2t*)&Ld[(sl + 1) * 264 + c0] = (h2t){ (_Float16)(a.y * ga0 + be0), (_Float16)(c.y * ga1 + be1) };
      *(h2t*)&Ld[(sl + 2) * 264 + c0] = (h2t){ (_Float16)(a.z * ga0 + be0), (_Float16)(c.z * ga1 + be1) };
      *(h2t*)&Ld[(sl + 3) * 264 + c0] = (h2t){ (_Float16)(a.w * ga0 + be0), (_Float16)(c.w * ga1 + be1) };
    }
  }
  __syncthreads();

  const int lane = tid & 63, wv = tid >> 6;       // 8 waves
  const int m = lane & 15, quad = lane >> 4;
  const _Float16* wrow[6];
  #pragma unroll
  for (int j = 0; j < 6; ++j)
    wrow[j] = W + (size_t)((wv + 8 * j) * 16 + m) * C_DIM + quad * 8;
  const _Float16* lp = &Ld[m * 264 + quad * 8];

  floatx4 acc[6][2];
  #pragma unroll
  for (int j = 0; j < 6; ++j) {
    acc[j][0] = (floatx4){0.f,0.f,0.f,0.f};
    acc[j][1] = (floatx4){0.f,0.f,0.f,0.f};
  }

  #pragma unroll 2
  for (int k0 = 0; k0 < C_DIM; k0 += 32) {
    half8 b0 = *(const half8*)(lp + k0);
    half8 b1 = *(const half8*)(lp + 16 * 264 + k0);
    #pragma unroll
    for (int j = 0; j < 6; ++j) {
      half8 a = *(const half8*)(wrow[j] + k0);
      acc[j][0] = __builtin_amdgcn_mfma_f32_16x16x32_f16(a, b0, acc[j][0], 0, 0, 0);
      acc[j][1] = __builtin_amdgcn_mfma_f32_16x16x32_f16(a, b1, acc[j][1], 0, 0, 0);
    }
  }

  __syncthreads();
  #pragma unroll
  for (int j = 0; j < 4; ++j) {
    const int ob = (wv + 8 * j) * 16 + quad * 4;  // 0..511
    const float bv0 = bias[ob], bv1 = bias[ob + 1],
                bv2 = bias[ob + 2], bv3 = bias[ob + 3];
    _Float16* dst = (ob < 256) ? qo : ko_;
    const int oo = ob & 255, n = oo >> 5, d0 = oo & 31;
    #pragma unroll
    for (int sub = 0; sub < 2; ++sub) {
      int s = s0 + sub * 16 + m;
      half4 h = { (_Float16)(acc[j][sub][0] + bv0), (_Float16)(acc[j][sub][1] + bv1),
                  (_Float16)(acc[j][sub][2] + bv2), (_Float16)(acc[j][sub][3] + bv3) };
      *(half4*)(dst + (((size_t)b * NHEADS + n) * S_LEN + s) * HDIM + d0) = h;
    }
  }
  _Float16* VLd = Ld;
  #pragma unroll
  for (int j = 4; j < 6; ++j) {
    const int ob = (wv + 8 * j) * 16 + quad * 4;  // 512..767
    const int lch = ob - 512;
    const float bv0 = bias[ob], bv1 = bias[ob + 1],
                bv2 = bias[ob + 2], bv3 = bias[ob + 3];
    #pragma unroll
    for (int sub = 0; sub < 2; ++sub) {
      int s = sub * 16 + m;
      VLd[(lch + 0) * 40 + s] = (_Float16)(acc[j][sub][0] + bv0);
      VLd[(lch + 1) * 40 + s] = (_Float16)(acc[j][sub][1] + bv1);
      VLd[(lch + 2) * 40 + s] = (_Float16)(acc[j][sub][2] + bv2);
      VLd[(lch + 3) * 40 + s] = (_Float16)(acc[j][sub][3] + bv3);
    }
  }
  __syncthreads();
  {
    const int ch = tid >> 1, sh = tid & 1;
    const int n = ch >> 5, d = ch & 31;
    _Float16* dst = vo + ((size_t)(b * NHEADS + n) * HDIM + d) * S_LEN + s0 + sh * 16;
    const _Float16* src = VLd + ch * 40 + sh * 16;
    *(half8*)(dst + 0) = *(const half8*)(src + 0);
    *(half8*)(dst + 8) = *(const half8*)(src + 8);
  }
}

// ---------------------------------------------------------------- Attention
// R12: software-pipelined inner loop. QK MFMAs for sub-step t+1 are issued
// BEFORE softmax(t), so QK latency hides under the previous step's
// exp2/pack/fdot chain (within-wave overlap that 2-waves/SIMD can't give).
// Geometry identical to R7 (128-key tiles, rotation, setprio, kh=1).
__global__ __launch_bounds__(512) void attn_kernel(
    const _Float16* __restrict__ q, const _Float16* __restrict__ k,
    const _Float16* __restrict__ v, _Float16* __restrict__ o)
{
  __shared__ __align__(16) _Float16 Kl[2][128 * 40];  // (kk, d) stride 40
  __shared__ __align__(16) _Float16 Vl[2][32 * 136];  // (d, kk) stride 136
  const int tid = threadIdx.x;
  const int lane = tid & 63, wv = tid >> 6;          // wv 0..7
  const int m = lane & 15, quad = lane >> 4;
  const int n = blockIdx.y, b = blockIdx.z;
  const int qc = blockIdx.x;
  const int q0 = qc * 256 + wv * 32;
  const int bh = b * NHEADS + n;

  const _Float16* qb = q + (size_t)bh * S_LEN * HDIM;
  const _Float16* kb = k + (size_t)bh * S_LEN * HDIM;
  const _Float16* vb = v + (size_t)bh * HDIM * S_LEN;

  half8 qfA = *(const half8*)(qb + (size_t)(q0 + m) * HDIM + quad * 8);
  half8 qfB = *(const half8*)(qb + (size_t)(q0 + 16 + m) * HDIM + quad * 8);

  const int krow = wv * 16 + (lane >> 2), kc = (lane & 3) * 8;
  const int vrow = wv * 4 + (lane >> 4), vc = (lane & 15) * 8;
  const _Float16* kg = kb + (size_t)krow * HDIM + kc;
  const _Float16* vg = vb + (size_t)vrow * S_LEN + vc;
  const int klds = krow * 40 + kc;
  const int vlds = vrow * 136 + vc;

  int4 kreg = *(const int4*)kg;
  int4 vreg = *(const int4*)vg;
  const _Float16* kgp = kg + 128 * HDIM;
  const _Float16* vgp = vg + 128;

  floatx4 oA0 = {0.f,0.f,0.f,0.f}, oA1 = oA0, oB0 = oA0, oB1 = oA0;
  float lA0 = 0.f, lA1 = 0.f, lB0 = 0.f, lB1 = 0.f;
  const fp16x2 one2 = { (__fp16)1.0f, (__fp16)1.0f };
  const floatx4 zz = {0.f,0.f,0.f,0.f};

  #pragma unroll 2
  for (int it = 0; it < 32; ++it) {          // 32 x 128 keys = 4096 (all)
    const int bufi = it & 1;
    *(int4*)(&Kl[bufi][klds]) = kreg;
    *(int4*)(&Vl[bufi][vlds]) = vreg;
    kreg = *(const int4*)kgp; kgp += 128 * HDIM;   // unconditional prefetch
    vreg = *(const int4*)vgp; vgp += 128;
    __syncthreads();
    const _Float16* Kb = Kl[bufi];
    const _Float16* Vb = Vl[bufi];

    // ---- software pipeline: QK(t+1) issued before softmax(t)+PV(t)
    half8 kf; half4 vf0, vf1;
    {
      const int tt = wv & 7;                 // t = 0 rotated
      kf  = *(const half8*)(Kb + (tt * 16 + m) * 40 + quad * 8);
      vf0 = *(const half4*)(Vb + m * 136 + tt * 16 + quad * 4);
      vf1 = *(const half4*)(Vb + (16 + m) * 136 + tt * 16 + quad * 4);
    }
    __builtin_amdgcn_s_setprio(1);
    floatx4 sA = __builtin_amdgcn_mfma_f32_16x16x32_f16(kf, qfA, zz, 0, 0, 0);
    floatx4 sB = __builtin_amdgcn_mfma_f32_16x16x32_f16(kf, qfB, zz, 0, 0, 0);
    __builtin_amdgcn_s_setprio(0);
    half4 pv0 = vf0, pv1 = vf1;

    #pragma unroll
    for (int t = 0; t < 8; ++t) {
      // capture step-t state
      floatx4 cA = sA, cB = sB;
      half4 cv0 = pv0, cv1 = pv1;
      // issue step-(t+1) QK ahead of step-t softmax
      if (t < 7) {
        const int tt = ((t + 1) + wv) & 7;
        kf  = *(const half8*)(Kb + (tt * 16 + m) * 40 + quad * 8);
        vf0 = *(const half4*)(Vb + m * 136 + tt * 16 + quad * 4);
        vf1 = *(const half4*)(Vb + (16 + m) * 136 + tt * 16 + quad * 4);
        __builtin_amdgcn_s_setprio(1);
        sA = __builtin_amdgcn_mfma_f32_16x16x32_f16(kf, qfA, zz, 0, 0, 0);
        sB = __builtin_amdgcn_mfma_f32_16x16x32_f16(kf, qfB, zz, 0, 0, 0);
        __builtin_amdgcn_s_setprio(0);
        pv0 = vf0; pv1 = vf1;
      }
      // softmax(t) + PV(t)
      float eA0 = __builtin_amdgcn_exp2f(cA[0]);
      float eA1 = __builtin_amdgcn_exp2f(cA[1]);
      float eA2 = __builtin_amdgcn_exp2f(cA[2]);
      float eA3 = __builtin_amdgcn_exp2f(cA[3]);
      float eB0 = __builtin_amdgcn_exp2f(cB[0]);
      float eB1 = __builtin_amdgcn_exp2f(cB[1]);
      float eB2 = __builtin_amdgcn_exp2f(cB[2]);
      float eB3 = __builtin_amdgcn_exp2f(cB[3]);
      half4 pA, pB;
      fp16x2 pAlo = __builtin_amdgcn_cvt_pkrtz(eA0, eA1);
      fp16x2 pAhi = __builtin_amdgcn_cvt_pkrtz(eA2, eA3);
      fp16x2 pBlo = __builtin_amdgcn_cvt_pkrtz(eB0, eB1);
      fp16x2 pBhi = __builtin_amdgcn_cvt_pkrtz(eB2, eB3);
      *(fp16x2*)&pA = pAlo; *((fp16x2*)&pA + 1) = pAhi;
      *(fp16x2*)&pB = pBlo; *((fp16x2*)&pB + 1) = pBhi;
      lA0 = __builtin_amdgcn_fdot2(pAlo, one2, lA0, false);
      lA1 = __builtin_amdgcn_fdot2(pAhi, one2, lA1, false);
      lB0 = __builtin_amdgcn_fdot2(pBlo, one2, lB0, false);
      lB1 = __builtin_amdgcn_fdot2(pBhi, one2, lB1, false);
      __builtin_amdgcn_s_setprio(1);
      oA0 = __builtin_amdgcn_mfma_f32_16x16x16f16(cv0, pA, oA0, 0, 0, 0);
      oA1 = __builtin_amdgcn_mfma_f32_16x16x16f16(cv1, pA, oA1, 0, 0, 0);
      oB0 = __builtin_amdgcn_mfma_f32_16x16x16f16(cv0, pB, oB0, 0, 0, 0);
      oB1 = __builtin_amdgcn_mfma_f32_16x16x16f16(cv1, pB, oB1, 0, 0, 0);
      __builtin_amdgcn_s_setprio(0);
    }
  }
  float lA = lA0 + lA1, lB = lB0 + lB1;
  lA += __shfl_xor(lA, 16, 64); lA += __shfl_xor(lA, 32, 64);
  lB += __shfl_xor(lB, 16, 64); lB += __shfl_xor(lB, 32, 64);
  const float rA = 1.f / lA, rB = 1.f / lB;
  _Float16* obase = o + ((size_t)bh * S_LEN) * HDIM;
  {
    _Float16* oh = obase + (size_t)(q0 + m) * HDIM;
    half4 h0 = { (_Float16)(oA0[0] * rA), (_Float16)(oA0[1] * rA),
                 (_Float16)(oA0[2] * rA), (_Float16)(oA0[3] * rA) };
    half4 h1 = { (_Float16)(oA1[0] * rA), (_Float16)(oA1[1] * rA),
                 (_Float16)(oA1[2] * rA), (_Float16)(oA1[3] * rA) };
    *(half4*)(oh + quad * 4) = h0;
    *(half4*)(oh + 16 + quad * 4) = h1;
  }
  {
    _Float16* oh = obase + (size_t)(q0 + 16 + m) * HDIM;
    half4 h0 = { (_Float16)(oB0[0] * rB), (_Float16)(oB0[1] * rB),
                 (_Float16)(oB0[2] * rB), (_Float16)(oB0[3] * rB) };
    half4 h1 = { (_Float16)(oB1[0] * rB), (_Float16)(oB1[1] * rB),
                 (_Float16)(oB1[2] * rB), (_Float16)(oB1[3] * rB) };
    *(half4*)(oh + quad * 4) = h0;
    *(half4*)(oh + 16 + quad * 4) = h1;
  }
}

// ---------------------------------------------------------------- Proj GEMM
// R6 state (unchanged): plain GEMM on normalized o. Grid (2,64,2).
__global__ __launch_bounds__(256) void proj_gemm(
    const _Float16* __restrict__ W, const float* __restrict__ bias,
    const _Float16* __restrict__ o,
    const float* __restrict__ x, float* __restrict__ out)
{
  const int tid = threadIdx.x;
  const int lane = tid & 63, wv = tid >> 6;
  const int m = lane & 15, quad = lane >> 4;
  const int mtb = blockIdx.x * 8 + wv * 2;   // 2 mt tiles per wave
  const int s0 = blockIdx.y * 64;
  const int b = blockIdx.z;

  const _Float16* wrow0 = W + (size_t)((mtb + 0) * 16 + m) * C_DIM + quad * 8;
  const _Float16* wrow1 = W + (size_t)((mtb + 1) * 16 + m) * C_DIM + quad * 8;
  floatx4 acc[2][4];
  #pragma unroll
  for (int j = 0; j < 2; ++j)
    #pragma unroll
    for (int s = 0; s < 4; ++s) acc[j][s] = (floatx4){0.f,0.f,0.f,0.f};

  #pragma unroll
  for (int k0 = 0; k0 < C_DIM; k0 += 32) {
    const int n = k0 >> 5;
    const int d0 = quad * 8;
    half8 bf[4];
    #pragma unroll
    for (int sub = 0; sub < 4; ++sub) {
      size_t idx = (((size_t)(b * NHEADS + n)) * S_LEN + s0 + sub * 16 + m) * HDIM + d0;
      bf[sub] = *(const half8*)(o + idx);
    }
    half8 af0 = *(const half8*)(wrow0 + k0);
    half8 af1 = *(const half8*)(wrow1 + k0);
    #pragma unroll
    for (int sub = 0; sub < 4; ++sub) {
      acc[0][sub] = __builtin_amdgcn_mfma_f32_16x16x32_f16(af0, bf[sub], acc[0][sub], 0, 0, 0);
      acc[1][sub] = __builtin_amdgcn_mfma_f32_16x16x32_f16(af1, bf[sub], acc[1][sub], 0, 0, 0);
    }
  }
  #pragma unroll
  for (int j = 0; j < 2; ++j)
    #pragma unroll
    for (int sub = 0; sub < 4; ++sub) {
      int s = s0 + sub * 16 + m;
      #pragma unroll
      for (int r = 0; r < 4; ++r) {
        int c = (mtb + j) * 16 + quad * 4 + r;
        size_t idx = ((size_t)b * C_DIM + c) * S_LEN + s;
        out[idx] = x[idx] + acc[j][sub][r] + bias[c];
      }
    }
}

// ---------------------------------------------------------------- launch
extern "C" void kernel_launch(void* const* d_in, const int* in_sizes, int n_in,
                              void* d_out, int out_size, void* d_ws, size_t ws_size,
                              hipStream_t stream) {
  const float* x        = (const float*)d_in[0];
  const float* gn_gamma = (const float*)d_in[1];
  const float* gn_beta  = (const float*)d_in[2];
  const float* qkv_w    = (const float*)d_in[3];
  const float* qkv_b    = (const float*)d_in[4];
  const float* proj_w   = (const float*)d_in[5];
  const float* proj_b   = (const float*)d_in[6];
  float* out = (float*)d_out;

  const size_t n1 = (size_t)2 * S_LEN * C_DIM;   // 2M elems = 4 MB f16
  char* ws = (char*)d_ws;
  _Float16* qx  = (_Float16*)ws;                 // (B,NH,S,hd)
  _Float16* kx  = qx + n1;                       // (B,NH,S,hd)
  _Float16* vx  = kx + n1;                       // (B,NH,hd,S)
  _Float16* wq  = vx + n1;                       // 768x256 f16
  _Float16* wp  = wq + 768 * 256;                // 256x256 f16
  float*    qbias = (float*)(wp + 256 * 256);    // 768 f32
  float*    pstat = qbias + 768;                 // 512*2 f32
  _Float16* ox  = (_Float16*)(pstat + 1024);     // (B,NH,S,hd) f16 = 4 MB

  prep_stats<<<769, 256, 0, stream>>>(qkv_w, proj_w, qkv_b, x, wq, wp, qbias, pstat);
  qkv_gn_gemm<<<dim3(128, 2), 512, 0, stream>>>(wq, qbias, x, gn_gamma, gn_beta, pstat, qx, kx, vx);
  attn_kernel<<<dim3(16, 8, 2), 512, 0, stream>>>(qx, kx, vx, ox);
  proj_gemm<<<dim3(2, 64, 2), 256, 0, stream>>>(wp, proj_b, ox, x, out);
}